// Round 1
// baseline (21247.112 us; speedup 1.0000x reference)
//
#include <hip/hip_runtime.h>
#include <hip/hip_bf16.h>
#include <math.h>

#define NNODES 8192
#define NEDGES 65536

constexpr int BO = 64, BM = 64, BK = 16;

// Generic fused 1x1-conv GEMM:  Y[O,M] = W[O,C] @ X[C,M]
// IN_MODE: 0 = direct X, 1 = edge concat [ave(xn), xe, grad(xn)], 2 = node concat [dxn_in(0..255), xn]
// LNT    : apply tanh((x-mean)*rstd) to input elements (global LN, stats in mr[0..1])
// STATS  : accumulate sum/sumsq of outputs into acc_stats (for the NEXT layer's LN)
// RESID  : Y = R + Hc * acc  (wave residual update)
// EPI    : 0 none, 1 +bias, 2 +bias then ELU
// TOUT   : write transposed  Y[m*ldOut + o]  (for lin2 -> d_out row-major)
template<int IN_MODE, bool LNT, bool STATS, bool RESID, int EPI, bool TOUT>
__global__ __launch_bounds__(256)
void gemm_k(const float* __restrict__ W, const float* __restrict__ X,
            float* __restrict__ Y, int C, int M,
            const float* __restrict__ xn, const float* __restrict__ xe,
            const int* __restrict__ Iidx, const int* __restrict__ Jidx,
            const float* __restrict__ mr, double* __restrict__ acc_stats,
            const float* __restrict__ R, float Hc,
            const float* __restrict__ bias, int ldOut)
{
    __shared__ float Ws[BK][BO + 1];
    __shared__ float Xs[BK][BM + 1];
    __shared__ int Is[BM], Js[BM];

    const int t   = threadIdx.x;
    const int bm0 = blockIdx.x * BM;
    const int bo0 = blockIdx.y * BO;

    if (IN_MODE == 1) {
        if (t < BM) { Is[t] = Iidx[bm0 + t]; Js[t] = Jidx[bm0 + t]; }
    }
    __syncthreads();

    const int tx = t & 15, ty = t >> 4;
    const int oB = TOUT ? tx * 4 : ty * 4;   // micro-tile base in O
    const int mB = TOUT ? ty * 4 : tx * 4;   // micro-tile base in M

    float mean = 0.f, rstd = 1.f;
    if (LNT) { mean = mr[0]; rstd = mr[1]; }

    // load mappings (coalesced)
    const int wO = t >> 2;          // [0,64)
    const int wC = (t & 3) * 4;     // {0,4,8,12}
    const int xK = t >> 4;          // [0,16)
    const int xM = (t & 15) * 4;    // {0..60}

    float acc[4][4] = {};

    for (int k0 = 0; k0 < C; k0 += BK) {
        // W tile -> Ws[k][o]
        #pragma unroll
        for (int i = 0; i < 4; ++i) {
            int c = k0 + wC + i;
            Ws[wC + i][wO] = (c < C) ? W[(size_t)(bo0 + wO) * C + c] : 0.f;
        }
        // X tile -> Xs[k][m]
        {
            int c = k0 + xK;
            #pragma unroll
            for (int i = 0; i < 4; ++i) {
                int m  = xM + i;
                int mg = bm0 + m;
                float v = 0.f;
                if (c < C) {
                    if (IN_MODE == 0) {
                        v = X[(size_t)c * M + mg];
                    } else if (IN_MODE == 1) {
                        if (c < 128)      v = 0.5f * (xn[c * NNODES + Is[m]] + xn[c * NNODES + Js[m]]);
                        else if (c < 256) v = xe[(size_t)(c - 128) * NEDGES + mg];
                        else              v = xn[(c - 256) * NNODES + Is[m]] - xn[(c - 256) * NNODES + Js[m]];
                    } else { // IN_MODE == 2
                        v = (c < 256) ? X[(size_t)c * M + mg] : xn[(c - 256) * NNODES + mg];
                    }
                    if (LNT) v = tanhf((v - mean) * rstd);
                }
                Xs[xK][m] = v;
            }
        }
        __syncthreads();
        #pragma unroll
        for (int kk = 0; kk < BK; ++kk) {
            float a[4], b[4];
            #pragma unroll
            for (int i = 0; i < 4; ++i) a[i] = Ws[kk][oB + i];
            #pragma unroll
            for (int j = 0; j < 4; ++j) b[j] = Xs[kk][mB + j];
            #pragma unroll
            for (int i = 0; i < 4; ++i)
                #pragma unroll
                for (int j = 0; j < 4; ++j)
                    acc[i][j] += a[i] * b[j];
        }
        __syncthreads();
    }

    float lsum = 0.f, lsq = 0.f;
    #pragma unroll
    for (int i = 0; i < 4; ++i) {
        #pragma unroll
        for (int j = 0; j < 4; ++j) {
            float v = acc[i][j];
            const int og = bo0 + oB + i;
            const size_t mg = (size_t)bm0 + mB + j;
            if (RESID)    v = R[(size_t)og * M + mg] + Hc * v;
            if (EPI >= 1) v += bias[og];
            if (EPI == 2) v = v > 0.f ? v : expf(v) - 1.f;
            if (TOUT) Y[mg * (size_t)ldOut + og] = v;
            else      Y[(size_t)og * M + mg] = v;
            if (STATS) { lsum += v; lsq += v * v; }
        }
    }

    if (STATS) {
        __shared__ float rs[256], rq[256];
        rs[t] = lsum; rq[t] = lsq;
        __syncthreads();
        for (int s = 128; s > 0; s >>= 1) {
            if (t < s) { rs[t] += rs[t + s]; rq[t] += rq[t + s]; }
            __syncthreads();
        }
        if (t == 0) {
            atomicAdd(&acc_stats[0], (double)rs[0]);
            atomicAdd(&acc_stats[1], (double)rq[0]);
        }
    }
}

__global__ void finalize_stats_k(const double* __restrict__ acc, float* __restrict__ mr, double invCnt)
{
    double mean = acc[0] * invCnt;
    double var  = acc[1] * invCnt - mean * mean;
    mr[0] = (float)mean;
    mr[1] = (float)(1.0 / sqrt(var + 1e-5));
}

// dxn rows 0..127: edge_ave = 0.5*(scatter I + scatter J); rows 128..255: edge_div = +I -J
__global__ __launch_bounds__(256)
void edge_scatter_k(const float* __restrict__ xe, const int* __restrict__ I,
                    const int* __restrict__ J, float* __restrict__ dxn)
{
    int idx = blockIdx.x * blockDim.x + threadIdx.x;   // [0, 128*E)
    int c = idx >> 16;
    int e = idx & (NEDGES - 1);
    float v = xe[(size_t)c * NEDGES + e];
    int a = I[e], b = J[e];
    atomicAdd(&dxn[(size_t)c * NNODES + a], 0.5f * v);
    atomicAdd(&dxn[(size_t)c * NNODES + b], 0.5f * v);
    atomicAdd(&dxn[(size_t)(c + 128) * NNODES + a], v);
    atomicAdd(&dxn[(size_t)(c + 128) * NNODES + b], -v);
}

__global__ __launch_bounds__(256)
void log_softmax_k(float* __restrict__ y)
{
    const int row = blockIdx.x;
    float* p = y + (size_t)row * NNODES;
    __shared__ float red[256];
    const int t = threadIdx.x;

    float m = -INFINITY;
    for (int i = t; i < NNODES; i += 256) m = fmaxf(m, p[i]);
    red[t] = m; __syncthreads();
    for (int s = 128; s > 0; s >>= 1) { if (t < s) red[t] = fmaxf(red[t], red[t + s]); __syncthreads(); }
    m = red[0]; __syncthreads();

    float ssum = 0.f;
    for (int i = t; i < NNODES; i += 256) ssum += expf(p[i] - m);
    red[t] = ssum; __syncthreads();
    for (int s = 128; s > 0; s >>= 1) { if (t < s) red[t] += red[t + s]; __syncthreads(); }
    const float lse = m + logf(red[0]);

    for (int i = t; i < NNODES; i += 256) p[i] -= lse;
}

__global__ void alpha_k(const float* __restrict__ a, float* __restrict__ out)
{
    out[0] = 1.f / (1.f + expf(-a[0]));
}

extern "C" void kernel_launch(void* const* d_in, const int* in_sizes, int n_in,
                              void* d_out, int out_size, void* d_ws, size_t ws_size,
                              hipStream_t stream)
{
    const float* xn_in = (const float*)d_in[0];
    const float* xe_in = (const float*)d_in[1];
    const float* K1N   = (const float*)d_in[2];
    const float* K2N   = (const float*)d_in[3];
    const float* K1E   = (const float*)d_in[4];
    const float* K2E   = (const float*)d_in[5];
    const float* KNc   = (const float*)d_in[6];
    const float* KE1   = (const float*)d_in[7];
    const float* KE2   = (const float*)d_in[8];
    const float* KN1   = (const float*)d_in[9];
    const float* KN2   = (const float*)d_in[10];
    const float* l1w   = (const float*)d_in[11];
    const float* l1b   = (const float*)d_in[12];
    const float* l2w   = (const float*)d_in[13];
    const float* l2b   = (const float*)d_in[14];
    const float* alpha = (const float*)d_in[15];
    const int*   I     = (const int*)d_in[16];
    const int*   J     = (const int*)d_in[17];
    float* out = (float*)d_out;

    char* ws = (char*)d_ws;
    float* xe_buf = (float*)ws;  ws += (size_t)128 * NEDGES * 4;   // 32 MB
    float* xn_buf = (float*)ws;  ws += (size_t)128 * NNODES * 4;   //  4 MB
    float* t_e    = (float*)ws;  ws += (size_t)256 * NEDGES * 4;   // 64 MB
    float* t_n    = (float*)ws;  ws += (size_t)256 * NNODES * 4;   //  8 MB
    float* dxn_in = (float*)ws;  ws += (size_t)256 * NNODES * 4;   //  8 MB
    double* sacc  = (double*)ws; ws += 256;
    float*  smr   = (float*)ws;  ws += 256;
    float* xnc = t_n;   // reused after the wave layers
    float* x1  = t_e;

    const dim3 blk(256);
    auto grd = [](int M, int O) { return dim3(M / BM, O / BO); };

    // ---- opening: node ----
    hipMemsetAsync(sacc, 0, 16, stream);
    gemm_k<0, false, true, false, 0, false><<<grd(NNODES, 128), blk, 0, stream>>>(
        K1N, xn_in, t_n, 3, NNODES, nullptr, nullptr, nullptr, nullptr,
        nullptr, sacc, nullptr, 0.f, nullptr, 0);
    finalize_stats_k<<<1, 1, 0, stream>>>(sacc, smr, 1.0 / (128.0 * NNODES));
    gemm_k<0, true, false, false, 0, false><<<grd(NNODES, 128), blk, 0, stream>>>(
        K2N, t_n, xn_buf, 128, NNODES, nullptr, nullptr, nullptr, nullptr,
        smr, nullptr, nullptr, 0.f, nullptr, 0);

    // ---- opening: edge ----
    hipMemsetAsync(sacc, 0, 16, stream);
    gemm_k<0, false, true, false, 0, false><<<grd(NEDGES, 128), blk, 0, stream>>>(
        K1E, xe_in, t_e, 16, NEDGES, nullptr, nullptr, nullptr, nullptr,
        nullptr, sacc, nullptr, 0.f, nullptr, 0);
    finalize_stats_k<<<1, 1, 0, stream>>>(sacc, smr, 1.0 / (128.0 * NEDGES));
    gemm_k<0, true, false, false, 0, false><<<grd(NEDGES, 128), blk, 0, stream>>>(
        K2E, t_e, xe_buf, 128, NEDGES, nullptr, nullptr, nullptr, nullptr,
        smr, nullptr, nullptr, 0.f, nullptr, 0);

    // ---- wave layers ----
    for (int l = 0; l < 8; ++l) {
        const float* ke1 = KE1 + (size_t)l * 256 * 384;
        const float* ke2 = KE2 + (size_t)l * 128 * 256;
        const float* kn1 = KN1 + (size_t)l * 256 * 384;
        const float* kn2 = KN2 + (size_t)l * 128 * 256;

        // edge double-layer
        hipMemsetAsync(sacc, 0, 16, stream);
        gemm_k<1, false, true, false, 0, false><<<grd(NEDGES, 256), blk, 0, stream>>>(
            ke1, nullptr, t_e, 384, NEDGES, xn_buf, xe_buf, I, J,
            nullptr, sacc, nullptr, 0.f, nullptr, 0);
        finalize_stats_k<<<1, 1, 0, stream>>>(sacc, smr, 1.0 / (256.0 * NEDGES));
        gemm_k<0, true, false, true, 0, false><<<grd(NEDGES, 128), blk, 0, stream>>>(
            ke2, t_e, xe_buf, 256, NEDGES, nullptr, nullptr, nullptr, nullptr,
            smr, nullptr, xe_buf, 0.1f, nullptr, 0);

        // scatter edges -> node features
        hipMemsetAsync(dxn_in, 0, (size_t)256 * NNODES * 4, stream);
        edge_scatter_k<<<dim3(128 * NEDGES / 256), blk, 0, stream>>>(xe_buf, I, J, dxn_in);

        // node double-layer
        hipMemsetAsync(sacc, 0, 16, stream);
        gemm_k<2, false, true, false, 0, false><<<grd(NNODES, 256), blk, 0, stream>>>(
            kn1, dxn_in, t_n, 384, NNODES, xn_buf, nullptr, nullptr, nullptr,
            nullptr, sacc, nullptr, 0.f, nullptr, 0);
        finalize_stats_k<<<1, 1, 0, stream>>>(sacc, smr, 1.0 / (256.0 * NNODES));
        gemm_k<0, true, false, true, 0, false><<<grd(NNODES, 128), blk, 0, stream>>>(
            kn2, t_n, xn_buf, 256, NNODES, nullptr, nullptr, nullptr, nullptr,
            smr, nullptr, xn_buf, 0.1f, nullptr, 0);
    }

    // ---- close + head ----
    gemm_k<0, false, false, false, 0, false><<<grd(NNODES, 128), blk, 0, stream>>>(
        KNc, xn_buf, xnc, 128, NNODES, nullptr, nullptr, nullptr, nullptr,
        nullptr, nullptr, nullptr, 0.f, nullptr, 0);
    gemm_k<0, false, false, false, 2, false><<<grd(NNODES, 256), blk, 0, stream>>>(
        l1w, xnc, x1, 128, NNODES, nullptr, nullptr, nullptr, nullptr,
        nullptr, nullptr, nullptr, 0.f, l1b, 0);
    gemm_k<0, false, false, false, 1, true><<<grd(NNODES, 8192), blk, 0, stream>>>(
        l2w, x1, out, 256, NNODES, nullptr, nullptr, nullptr, nullptr,
        nullptr, nullptr, nullptr, 0.f, l2b, NNODES);

    log_softmax_k<<<dim3(NNODES), blk, 0, stream>>>(out);
    alpha_k<<<1, 1, 0, stream>>>(alpha, out + (size_t)NNODES * NNODES);
}

// Round 2
// 9314.650 us; speedup vs baseline: 2.2810x; 2.2810x over previous
//
#include <hip/hip_runtime.h>
#include <hip/hip_bf16.h>
#include <math.h>

#define NNODES 8192
#define NEDGES 65536

constexpr int BO = 64, BM = 64, BK = 16;

// Generic fused 1x1-conv GEMM:  Y[O,M] = W[O,C] @ X[C,M]
// IN_MODE: 0 = direct X, 1 = edge concat [ave(xn), xe, grad(xn)], 2 = node concat [dxn_in(0..255), xn]
// LNT    : apply tanh((x-mean)*rstd) to input elements (global LN, stats in mr[0..1])
// STATS  : accumulate sum/sumsq of outputs into acc_stats (for the NEXT layer's LN)
// RESID  : Y = R + Hc * acc  (wave residual update)
// EPI    : 0 none, 1 +bias, 2 +bias then ELU
// TOUT   : write transposed  Y[m*ldOut + o]  (for lin2 -> d_out row-major)
// Y2     : if non-null, ALSO write edge-major transposed copy Y2[m*128 + o]
template<int IN_MODE, bool LNT, bool STATS, bool RESID, int EPI, bool TOUT>
__global__ __launch_bounds__(256)
void gemm_k(const float* __restrict__ W, const float* __restrict__ X,
            float* __restrict__ Y, int C, int M,
            const float* __restrict__ xn, const float* __restrict__ xe,
            const int* __restrict__ Iidx, const int* __restrict__ Jidx,
            const float* __restrict__ mr, double* __restrict__ acc_stats,
            const float* __restrict__ R, float Hc,
            const float* __restrict__ bias, int ldOut,
            float* __restrict__ Y2)
{
    __shared__ float Ws[BK][BO + 1];
    __shared__ float Xs[BK][BM + 1];
    __shared__ int Is[BM], Js[BM];

    const int t   = threadIdx.x;
    const int bm0 = blockIdx.x * BM;
    const int bo0 = blockIdx.y * BO;

    if (IN_MODE == 1) {
        if (t < BM) { Is[t] = Iidx[bm0 + t]; Js[t] = Jidx[bm0 + t]; }
    }
    __syncthreads();

    const int tx = t & 15, ty = t >> 4;
    const int oB = TOUT ? tx * 4 : ty * 4;   // micro-tile base in O
    const int mB = TOUT ? ty * 4 : tx * 4;   // micro-tile base in M

    float mean = 0.f, rstd = 1.f;
    if (LNT) { mean = mr[0]; rstd = mr[1]; }

    // load mappings (coalesced)
    const int wO = t >> 2;          // [0,64)
    const int wC = (t & 3) * 4;     // {0,4,8,12}
    const int xK = t >> 4;          // [0,16)
    const int xM = (t & 15) * 4;    // {0..60}

    float acc[4][4] = {};

    for (int k0 = 0; k0 < C; k0 += BK) {
        // W tile -> Ws[k][o]
        #pragma unroll
        for (int i = 0; i < 4; ++i) {
            int c = k0 + wC + i;
            Ws[wC + i][wO] = (c < C) ? W[(size_t)(bo0 + wO) * C + c] : 0.f;
        }
        // X tile -> Xs[k][m]
        {
            int c = k0 + xK;
            #pragma unroll
            for (int i = 0; i < 4; ++i) {
                int m  = xM + i;
                int mg = bm0 + m;
                float v = 0.f;
                if (c < C) {
                    if (IN_MODE == 0) {
                        v = X[(size_t)c * M + mg];
                    } else if (IN_MODE == 1) {
                        if (c < 128)      v = 0.5f * (xn[c * NNODES + Is[m]] + xn[c * NNODES + Js[m]]);
                        else if (c < 256) v = xe[(size_t)(c - 128) * NEDGES + mg];
                        else              v = xn[(c - 256) * NNODES + Is[m]] - xn[(c - 256) * NNODES + Js[m]];
                    } else { // IN_MODE == 2
                        v = (c < 256) ? X[(size_t)c * M + mg] : xn[(c - 256) * NNODES + mg];
                    }
                    if (LNT) v = tanhf((v - mean) * rstd);
                }
                Xs[xK][m] = v;
            }
        }
        __syncthreads();
        #pragma unroll
        for (int kk = 0; kk < BK; ++kk) {
            float a[4], b[4];
            #pragma unroll
            for (int i = 0; i < 4; ++i) a[i] = Ws[kk][oB + i];
            #pragma unroll
            for (int j = 0; j < 4; ++j) b[j] = Xs[kk][mB + j];
            #pragma unroll
            for (int i = 0; i < 4; ++i)
                #pragma unroll
                for (int j = 0; j < 4; ++j)
                    acc[i][j] += a[i] * b[j];
        }
        __syncthreads();
    }

    float lsum = 0.f, lsq = 0.f;
    #pragma unroll
    for (int i = 0; i < 4; ++i) {
        #pragma unroll
        for (int j = 0; j < 4; ++j) {
            float v = acc[i][j];
            const int og = bo0 + oB + i;
            const size_t mg = (size_t)bm0 + mB + j;
            if (RESID)    v = R[(size_t)og * M + mg] + Hc * v;
            if (EPI >= 1) v += bias[og];
            if (EPI == 2) v = v > 0.f ? v : expf(v) - 1.f;
            if (TOUT) Y[mg * (size_t)ldOut + og] = v;
            else      Y[(size_t)og * M + mg] = v;
            if (Y2)   Y2[mg * 128 + og] = v;
            if (STATS) { lsum += v; lsq += v * v; }
        }
    }

    if (STATS) {
        __shared__ float rs[256], rq[256];
        rs[t] = lsum; rq[t] = lsq;
        __syncthreads();
        for (int s = 128; s > 0; s >>= 1) {
            if (t < s) { rs[t] += rs[t + s]; rq[t] += rq[t + s]; }
            __syncthreads();
        }
        if (t == 0) {
            atomicAdd(&acc_stats[0], (double)rs[0]);
            atomicAdd(&acc_stats[1], (double)rq[0]);
        }
    }
}

__global__ void finalize_stats_k(const double* __restrict__ acc, float* __restrict__ mr, double invCnt)
{
    double mean = acc[0] * invCnt;
    double var  = acc[1] * invCnt - mean * mean;
    mr[0] = (float)mean;
    mr[1] = (float)(1.0 / sqrt(var + 1e-5));
}

// ---------------- CSR build (per call; ws is re-poisoned between calls) ------
__global__ __launch_bounds__(256)
void csr_count_k(const int* __restrict__ I, const int* __restrict__ J, int* __restrict__ deg)
{
    int e = blockIdx.x * 256 + threadIdx.x;
    atomicAdd(&deg[I[e]], 1);
    atomicAdd(&deg[J[e]], 1);
}

// single block of 1024 threads: exclusive scan of deg[8192] -> rowp[8193], copy to cur
__global__ __launch_bounds__(1024)
void csr_scan_k(const int* __restrict__ deg, int* __restrict__ rowp, int* __restrict__ cur)
{
    __shared__ int part[1024];
    const int t = threadIdx.x;
    const int base = t * 8;
    int s = 0;
    #pragma unroll
    for (int i = 0; i < 8; ++i) s += deg[base + i];
    part[t] = s; __syncthreads();
    for (int off = 1; off < 1024; off <<= 1) {
        int v = (t >= off) ? part[t - off] : 0;
        __syncthreads();
        part[t] += v;
        __syncthreads();
    }
    int run = (t == 0) ? 0 : part[t - 1];
    #pragma unroll
    for (int i = 0; i < 8; ++i) {
        rowp[base + i] = run; cur[base + i] = run;
        run += deg[base + i];
    }
    if (t == 1023) rowp[8192] = run;
}

__global__ __launch_bounds__(256)
void csr_fill_k(const int* __restrict__ I, const int* __restrict__ J,
                int* __restrict__ cur, int* __restrict__ ent)
{
    int e = blockIdx.x * 256 + threadIdx.x;
    int p = atomicAdd(&cur[I[e]], 1); ent[p] = e;                      // sign +
    int q = atomicAdd(&cur[J[e]], 1); ent[q] = e | (int)0x80000000;    // sign -
}

// dxn rows 0..127: edge_ave = 0.5*sum(both endpoints); rows 128..255: edge_div = +I -J
// TRANS: xe is edge-major [E][128] (coalesced); else channel-major [128][E]
template<bool TRANS>
__global__ __launch_bounds__(128)
void gather_k(const float* __restrict__ xe, const int* __restrict__ rowp,
              const int* __restrict__ ent, float* __restrict__ dxn)
{
    const int n = blockIdx.x;
    const int c = threadIdx.x;
    const int b = rowp[n], e2 = rowp[n + 1];
    float ave = 0.f, dv = 0.f;
    for (int k = b; k < e2; ++k) {
        int v = ent[k];
        int e = v & 0x7fffffff;
        float x = TRANS ? xe[(size_t)e * 128 + c] : xe[(size_t)c * NEDGES + e];
        ave += x;
        dv  += (v < 0) ? -x : x;
    }
    dxn[(size_t)c * NNODES + n] = 0.5f * ave;
    dxn[(size_t)(c + 128) * NNODES + n] = dv;
}

__global__ __launch_bounds__(256)
void log_softmax_k(float* __restrict__ y)
{
    const int row = blockIdx.x;
    float* p = y + (size_t)row * NNODES;
    __shared__ float red[256];
    const int t = threadIdx.x;

    float m = -INFINITY;
    for (int i = t; i < NNODES; i += 256) m = fmaxf(m, p[i]);
    red[t] = m; __syncthreads();
    for (int s = 128; s > 0; s >>= 1) { if (t < s) red[t] = fmaxf(red[t], red[t + s]); __syncthreads(); }
    m = red[0]; __syncthreads();

    float ssum = 0.f;
    for (int i = t; i < NNODES; i += 256) ssum += expf(p[i] - m);
    red[t] = ssum; __syncthreads();
    for (int s = 128; s > 0; s >>= 1) { if (t < s) red[t] += red[t + s]; __syncthreads(); }
    const float lse = m + logf(red[0]);

    for (int i = t; i < NNODES; i += 256) p[i] -= lse;
}

__global__ void alpha_k(const float* __restrict__ a, float* __restrict__ out)
{
    out[0] = 1.f / (1.f + expf(-a[0]));
}

extern "C" void kernel_launch(void* const* d_in, const int* in_sizes, int n_in,
                              void* d_out, int out_size, void* d_ws, size_t ws_size,
                              hipStream_t stream)
{
    const float* xn_in = (const float*)d_in[0];
    const float* xe_in = (const float*)d_in[1];
    const float* K1N   = (const float*)d_in[2];
    const float* K2N   = (const float*)d_in[3];
    const float* K1E   = (const float*)d_in[4];
    const float* K2E   = (const float*)d_in[5];
    const float* KNc   = (const float*)d_in[6];
    const float* KE1   = (const float*)d_in[7];
    const float* KE2   = (const float*)d_in[8];
    const float* KN1   = (const float*)d_in[9];
    const float* KN2   = (const float*)d_in[10];
    const float* l1w   = (const float*)d_in[11];
    const float* l1b   = (const float*)d_in[12];
    const float* l2w   = (const float*)d_in[13];
    const float* l2b   = (const float*)d_in[14];
    const float* alpha = (const float*)d_in[15];
    const int*   I     = (const int*)d_in[16];
    const int*   J     = (const int*)d_in[17];
    float* out = (float*)d_out;

    char* ws = (char*)d_ws;
    float* xe_buf = (float*)ws;  ws += (size_t)128 * NEDGES * 4;   // 32 MB
    float* xn_buf = (float*)ws;  ws += (size_t)128 * NNODES * 4;   //  4 MB
    float* t_e    = (float*)ws;  ws += (size_t)256 * NEDGES * 4;   // 64 MB
    float* t_n    = (float*)ws;  ws += (size_t)256 * NNODES * 4;   //  8 MB
    float* dxn_in = (float*)ws;  ws += (size_t)256 * NNODES * 4;   //  8 MB
    int*   deg    = (int*)ws;    ws += (size_t)NNODES * 4;
    int*   rowp   = (int*)ws;    ws += (size_t)(NNODES + 2) * 4;
    int*   cur    = (int*)ws;    ws += (size_t)NNODES * 4;
    int*   ent    = (int*)ws;    ws += (size_t)2 * NEDGES * 4;     // 512 KB
    double* sacc  = (double*)ws; ws += 256;
    float*  smr   = (float*)ws;  ws += 256;
    float* xe_t   = (float*)ws;  // optional 32 MB edge-major copy
    const bool useT = ((size_t)((char*)xe_t - (char*)d_ws) + (size_t)NEDGES * 128 * 4) <= ws_size;

    float* xnc = t_n;   // reused after the wave layers
    float* x1  = t_e;

    const dim3 blk(256);
    auto grd = [](int M, int O) { return dim3(M / BM, O / BO); };

    // ---- CSR build ----
    hipMemsetAsync(deg, 0, (size_t)NNODES * 4, stream);
    csr_count_k<<<dim3(NEDGES / 256), blk, 0, stream>>>(I, J, deg);
    csr_scan_k<<<dim3(1), dim3(1024), 0, stream>>>(deg, rowp, cur);
    csr_fill_k<<<dim3(NEDGES / 256), blk, 0, stream>>>(I, J, cur, ent);

    // ---- opening: node ----
    hipMemsetAsync(sacc, 0, 16, stream);
    gemm_k<0, false, true, false, 0, false><<<grd(NNODES, 128), blk, 0, stream>>>(
        K1N, xn_in, t_n, 3, NNODES, nullptr, nullptr, nullptr, nullptr,
        nullptr, sacc, nullptr, 0.f, nullptr, 0, nullptr);
    finalize_stats_k<<<1, 1, 0, stream>>>(sacc, smr, 1.0 / (128.0 * NNODES));
    gemm_k<0, true, false, false, 0, false><<<grd(NNODES, 128), blk, 0, stream>>>(
        K2N, t_n, xn_buf, 128, NNODES, nullptr, nullptr, nullptr, nullptr,
        smr, nullptr, nullptr, 0.f, nullptr, 0, nullptr);

    // ---- opening: edge ----
    hipMemsetAsync(sacc, 0, 16, stream);
    gemm_k<0, false, true, false, 0, false><<<grd(NEDGES, 128), blk, 0, stream>>>(
        K1E, xe_in, t_e, 16, NEDGES, nullptr, nullptr, nullptr, nullptr,
        nullptr, sacc, nullptr, 0.f, nullptr, 0, nullptr);
    finalize_stats_k<<<1, 1, 0, stream>>>(sacc, smr, 1.0 / (128.0 * NEDGES));
    gemm_k<0, true, false, false, 0, false><<<grd(NEDGES, 128), blk, 0, stream>>>(
        K2E, t_e, xe_buf, 128, NEDGES, nullptr, nullptr, nullptr, nullptr,
        smr, nullptr, nullptr, 0.f, nullptr, 0, nullptr);

    // ---- wave layers ----
    for (int l = 0; l < 8; ++l) {
        const float* ke1 = KE1 + (size_t)l * 256 * 384;
        const float* ke2 = KE2 + (size_t)l * 128 * 256;
        const float* kn1 = KN1 + (size_t)l * 256 * 384;
        const float* kn2 = KN2 + (size_t)l * 128 * 256;

        // edge double-layer
        hipMemsetAsync(sacc, 0, 16, stream);
        gemm_k<1, false, true, false, 0, false><<<grd(NEDGES, 256), blk, 0, stream>>>(
            ke1, nullptr, t_e, 384, NEDGES, xn_buf, xe_buf, I, J,
            nullptr, sacc, nullptr, 0.f, nullptr, 0, nullptr);
        finalize_stats_k<<<1, 1, 0, stream>>>(sacc, smr, 1.0 / (256.0 * NEDGES));
        gemm_k<0, true, false, true, 0, false><<<grd(NEDGES, 128), blk, 0, stream>>>(
            ke2, t_e, xe_buf, 256, NEDGES, nullptr, nullptr, nullptr, nullptr,
            smr, nullptr, xe_buf, 0.1f, nullptr, 0, useT ? xe_t : nullptr);

        // gather edges -> node features (CSR, no atomics)
        if (useT) gather_k<true ><<<dim3(NNODES), dim3(128), 0, stream>>>(xe_t,  rowp, ent, dxn_in);
        else      gather_k<false><<<dim3(NNODES), dim3(128), 0, stream>>>(xe_buf, rowp, ent, dxn_in);

        // node double-layer
        hipMemsetAsync(sacc, 0, 16, stream);
        gemm_k<2, false, true, false, 0, false><<<grd(NNODES, 256), blk, 0, stream>>>(
            kn1, dxn_in, t_n, 384, NNODES, xn_buf, nullptr, nullptr, nullptr,
            nullptr, sacc, nullptr, 0.f, nullptr, 0, nullptr);
        finalize_stats_k<<<1, 1, 0, stream>>>(sacc, smr, 1.0 / (256.0 * NNODES));
        gemm_k<0, true, false, true, 0, false><<<grd(NNODES, 128), blk, 0, stream>>>(
            kn2, t_n, xn_buf, 256, NNODES, nullptr, nullptr, nullptr, nullptr,
            smr, nullptr, xn_buf, 0.1f, nullptr, 0, nullptr);
    }

    // ---- close + head ----
    gemm_k<0, false, false, false, 0, false><<<grd(NNODES, 128), blk, 0, stream>>>(
        KNc, xn_buf, xnc, 128, NNODES, nullptr, nullptr, nullptr, nullptr,
        nullptr, nullptr, nullptr, 0.f, nullptr, 0, nullptr);
    gemm_k<0, false, false, false, 2, false><<<grd(NNODES, 256), blk, 0, stream>>>(
        l1w, xnc, x1, 128, NNODES, nullptr, nullptr, nullptr, nullptr,
        nullptr, nullptr, nullptr, 0.f, l1b, 0, nullptr);
    gemm_k<0, false, false, false, 1, true><<<grd(NNODES, 8192), blk, 0, stream>>>(
        l2w, x1, out, 256, NNODES, nullptr, nullptr, nullptr, nullptr,
        nullptr, nullptr, nullptr, 0.f, l2b, NNODES, nullptr);

    log_softmax_k<<<dim3(NNODES), blk, 0, stream>>>(out);
    alpha_k<<<1, 1, 0, stream>>>(alpha, out + (size_t)NNODES * NNODES);
}

// Round 5
// 2657.242 us; speedup vs baseline: 7.9959x; 3.5054x over previous
//
#include <hip/hip_runtime.h>
#include <math.h>

#define NNODES 8192
#define NEDGES 65536

typedef __attribute__((ext_vector_type(8))) short bf16x8;
typedef __attribute__((ext_vector_type(4))) float f32x4;

__device__ __forceinline__ float b2f(short s) {
    unsigned int u = ((unsigned int)(unsigned short)s) << 16;
    float f; __builtin_memcpy(&f, &u, 4); return f;
}
__device__ __forceinline__ short f2b(float f) {
    unsigned int u; __builtin_memcpy(&u, &f, 4);
    u = (u + 0x7fffu + ((u >> 16) & 1u)) >> 16;
    return (short)u;
}

__device__ __forceinline__ void async_copy16(const void* g, void* l) {
    __builtin_amdgcn_global_load_lds(
        (const __attribute__((address_space(1))) void*)g,
        (__attribute__((address_space(3))) void*)l, 16, 0, 0);
}

// ---------------------------------------------------------------------------
// MFMA GEMM:  Y[m][o] = sum_c X[m][c] * W[o][c]   (+ epilogue)
// A-frag = X rows (m), B-frag = W rows (o). 128x128 tile, 4 waves, BK=32.
// XMODE: 0 = X direct bf16 [M][C] via global_load_lds
//        1 = X bf16 [M][C] with tanh((x-mean)*rstd) applied on load
//        2 = edge concat [0.5*(xn[I]+xn[J]) | xe | xn[I]-xn[J]], C=384
// STATS: accumulate sum/sumsq of outputs into acc_stats (for next LN)
// RESID: v = Rres[m][o] + Hc*acc
// EPI  : 0 none, 1 +bias, 2 +bias,ELU
// OUTF32: write float to Y[m*ldOut+o] (else bf16 to Y[m*ldY+o])
// LDS chunk swizzle: physical chunk p of row r holds logical K-chunk (p - (r>>1))&3
// ---------------------------------------------------------------------------
template<int XMODE, bool STATS, bool RESID, int EPI, bool OUTF32>
__global__ __launch_bounds__(256)
void mfma_gemm_k(const short* __restrict__ Wg, const short* __restrict__ Xg,
                 void* __restrict__ Yv, int C, int ldY,
                 const short* __restrict__ xnB, const short* __restrict__ xeB,
                 const int* __restrict__ Iidx, const int* __restrict__ Jidx,
                 const float* __restrict__ mr, double* __restrict__ acc_stats,
                 const short* __restrict__ Rres, float Hc,
                 const float* __restrict__ bias, int ldOut)
{
    __shared__ __attribute__((aligned(16))) short Xs[128 * 32];
    __shared__ __attribute__((aligned(16))) short Ws[128 * 32];
    __shared__ float rs[256], rq[256];

    const int t    = threadIdx.x;
    const int m0   = blockIdx.x * 128;
    const int o0   = blockIdx.y * 128;
    const int wave = t >> 6, lane = t & 63;
    const int wm   = wave >> 1, wn = wave & 1;
    const int lr   = lane & 15, kg = lane >> 4;

    float mean = 0.f, rstd = 1.f;
    if (XMODE == 1) { mean = mr[0]; rstd = mr[1]; }

    f32x4 acc[4][4];
    #pragma unroll
    for (int i = 0; i < 4; ++i)
        #pragma unroll
        for (int n = 0; n < 4; ++n)
            acc[i][n] = (f32x4){0.f, 0.f, 0.f, 0.f};

    for (int k0 = 0; k0 < C; k0 += 32) {
        // ---- stage W tile (always direct async copy) ----
        #pragma unroll
        for (int h = 0; h < 2; ++h) {
            int s  = t + h * 256;
            int r  = s >> 2;
            int kc = ((s & 3) - (r >> 1)) & 3;
            async_copy16(Wg + (size_t)(o0 + r) * C + k0 + kc * 8,
                         (char*)Ws + h * 4096 + wave * 1024);
        }
        // ---- stage X tile ----
        if (XMODE == 0) {
            #pragma unroll
            for (int h = 0; h < 2; ++h) {
                int s  = t + h * 256;
                int r  = s >> 2;
                int kc = ((s & 3) - (r >> 1)) & 3;
                async_copy16(Xg + (size_t)(m0 + r) * C + k0 + kc * 8,
                             (char*)Xs + h * 4096 + wave * 1024);
            }
        } else {
            #pragma unroll
            for (int h = 0; h < 2; ++h) {
                int s = t + h * 256;
                int r = s >> 2, kc = s & 3;
                int p = (kc + (r >> 1)) & 3;
                int c0 = k0 + kc * 8;
                bf16x8 o8;
                if (XMODE == 1) {
                    bf16x8 x = *(const bf16x8*)(Xg + (size_t)(m0 + r) * C + c0);
                    #pragma unroll
                    for (int j = 0; j < 8; ++j) {
                        float f = b2f(x[j]);
                        o8[j] = f2b(tanhf((f - mean) * rstd));
                    }
                } else { // XMODE == 2, C = 384
                    int e = m0 + r;
                    if (c0 < 128) {
                        bf16x8 xa = *(const bf16x8*)(xnB + (size_t)Iidx[e] * 128 + c0);
                        bf16x8 xb = *(const bf16x8*)(xnB + (size_t)Jidx[e] * 128 + c0);
                        #pragma unroll
                        for (int j = 0; j < 8; ++j) o8[j] = f2b(0.5f * (b2f(xa[j]) + b2f(xb[j])));
                    } else if (c0 < 256) {
                        o8 = *(const bf16x8*)(xeB + (size_t)e * 128 + (c0 - 128));
                    } else {
                        bf16x8 xa = *(const bf16x8*)(xnB + (size_t)Iidx[e] * 128 + (c0 - 256));
                        bf16x8 xb = *(const bf16x8*)(xnB + (size_t)Jidx[e] * 128 + (c0 - 256));
                        #pragma unroll
                        for (int j = 0; j < 8; ++j) o8[j] = f2b(b2f(xa[j]) - b2f(xb[j]));
                    }
                }
                *(bf16x8*)&Xs[r * 32 + p * 8] = o8;
            }
        }
        __syncthreads();   // drains vmcnt (global_load_lds) / lgkmcnt (ds_write)

        bf16x8 a[4], b[4];
        #pragma unroll
        for (int i = 0; i < 4; ++i) {
            int ra = wm * 64 + i * 16 + lr;
            int pa = (kg + (ra >> 1)) & 3;
            a[i] = *(const bf16x8*)&Xs[ra * 32 + pa * 8];
            int rb = wn * 64 + i * 16 + lr;
            int pb = (kg + (rb >> 1)) & 3;
            b[i] = *(const bf16x8*)&Ws[rb * 32 + pb * 8];
        }
        #pragma unroll
        for (int i = 0; i < 4; ++i)
            #pragma unroll
            for (int n = 0; n < 4; ++n)
                acc[i][n] = __builtin_amdgcn_mfma_f32_16x16x32_bf16(a[i], b[n], acc[i][n], 0, 0, 0);
        __syncthreads();
    }

    // ---- epilogue ----
    float lsum = 0.f, lsq = 0.f;
    #pragma unroll
    for (int i = 0; i < 4; ++i) {
        #pragma unroll
        for (int n = 0; n < 4; ++n) {
            #pragma unroll
            for (int r = 0; r < 4; ++r) {
                float v = acc[i][n][r];
                const int m = m0 + wm * 64 + i * 16 + kg * 4 + r;
                const int o = o0 + wn * 64 + n * 16 + lr;
                if (RESID)    v = b2f(Rres[(size_t)m * ldY + o]) + Hc * v;
                if (EPI >= 1) v += bias[o];
                if (EPI == 2) v = v > 0.f ? v : expf(v) - 1.f;
                if (OUTF32) ((float*)Yv)[(size_t)m * ldOut + o] = v;
                else        ((short*)Yv)[(size_t)m * ldY + o] = f2b(v);
                if (STATS) { lsum += v; lsq += v * v; }
            }
        }
    }

    if (STATS) {
        rs[t] = lsum; rq[t] = lsq;
        __syncthreads();
        for (int s = 128; s > 0; s >>= 1) {
            if (t < s) { rs[t] += rs[t + s]; rq[t] += rq[t + s]; }
            __syncthreads();
        }
        if (t == 0) {
            atomicAdd(&acc_stats[0], (double)rs[0]);
            atomicAdd(&acc_stats[1], (double)rq[0]);
        }
    }
}

// Opening conv1 (tiny C): Y[m][o] bf16 (o<128) from W[128][C] f32, X[C][M] f32, + stats
__global__ __launch_bounds__(256)
void open_gemm_k(const float* __restrict__ W, const float* __restrict__ X,
                 short* __restrict__ Y, int C, int M, double* __restrict__ acc_stats)
{
    __shared__ float rs[256], rq[256];
    const int t = threadIdx.x;
    const int o = t & 127;
    const int m = blockIdx.x * 2 + (t >> 7);
    float acc = 0.f;
    for (int c = 0; c < C; ++c) acc += W[o * C + c] * X[(size_t)c * M + m];
    Y[(size_t)m * 128 + o] = f2b(acc);
    rs[t] = acc; rq[t] = acc * acc;
    __syncthreads();
    for (int s = 128; s > 0; s >>= 1) {
        if (t < s) { rs[t] += rs[t + s]; rq[t] += rq[t + s]; }
        __syncthreads();
    }
    if (t == 0) {
        atomicAdd(&acc_stats[0], (double)rs[0]);
        atomicAdd(&acc_stats[1], (double)rq[0]);
    }
}

__global__ void finalize_stats_k(const double* __restrict__ acc, float* __restrict__ mr, double invCnt)
{
    double mean = acc[0] * invCnt;
    double var  = acc[1] * invCnt - mean * mean;
    mr[0] = (float)mean;
    mr[1] = (float)(1.0 / sqrt(var + 1e-5));
}

__global__ void cvt_bf16_k(const float* __restrict__ in, short* __restrict__ out, int n)
{
    int i = blockIdx.x * 256 + threadIdx.x;
    if (i < n) out[i] = f2b(in[i]);
}

// ---------------- CSR build ------------------------------------------------
__global__ __launch_bounds__(256)
void csr_count_k(const int* __restrict__ I, const int* __restrict__ J, int* __restrict__ deg)
{
    int e = blockIdx.x * 256 + threadIdx.x;
    atomicAdd(&deg[I[e]], 1);
    atomicAdd(&deg[J[e]], 1);
}

__global__ __launch_bounds__(1024)
void csr_scan_k(const int* __restrict__ deg, int* __restrict__ rowp, int* __restrict__ cur)
{
    __shared__ int part[1024];
    const int t = threadIdx.x;
    const int base = t * 8;
    int s = 0;
    #pragma unroll
    for (int i = 0; i < 8; ++i) s += deg[base + i];
    part[t] = s; __syncthreads();
    for (int off = 1; off < 1024; off <<= 1) {
        int v = (t >= off) ? part[t - off] : 0;
        __syncthreads();
        part[t] += v;
        __syncthreads();
    }
    int run = (t == 0) ? 0 : part[t - 1];
    #pragma unroll
    for (int i = 0; i < 8; ++i) {
        rowp[base + i] = run; cur[base + i] = run;
        run += deg[base + i];
    }
    if (t == 1023) rowp[8192] = run;
}

__global__ __launch_bounds__(256)
void csr_fill_k(const int* __restrict__ I, const int* __restrict__ J,
                int* __restrict__ cur, int* __restrict__ ent)
{
    int e = blockIdx.x * 256 + threadIdx.x;
    int p = atomicAdd(&cur[I[e]], 1); ent[p] = e;
    int q = atomicAdd(&cur[J[e]], 1); ent[q] = e | (int)0x80000000;
}

// node concat: dxn[n][0:128]=0.5*sum(edges), [128:256]=div, [256:384]=xn
__global__ __launch_bounds__(128)
void gather_node_k(const short* __restrict__ xe, const short* __restrict__ xn,
                   const int* __restrict__ rowp, const int* __restrict__ ent,
                   short* __restrict__ dxn)
{
    const int n = blockIdx.x;
    const int c = threadIdx.x;
    const int b = rowp[n], e2 = rowp[n + 1];
    float ave = 0.f, dv = 0.f;
    for (int k = b; k < e2; ++k) {
        int v = ent[k];
        int e = v & 0x7fffffff;
        float x = b2f(xe[(size_t)e * 128 + c]);
        ave += x;
        dv  += (v < 0) ? -x : x;
    }
    size_t base = (size_t)n * 384;
    dxn[base + c]       = f2b(0.5f * ave);
    dxn[base + 128 + c] = f2b(dv);
    dxn[base + 256 + c] = xn[(size_t)n * 128 + c];
}

__global__ __launch_bounds__(256)
void log_softmax_k(float* __restrict__ y)
{
    const int row = blockIdx.x;
    float* p = y + (size_t)row * NNODES;
    __shared__ float red[256];
    const int t = threadIdx.x;

    float m = -INFINITY;
    for (int i = t; i < NNODES; i += 256) m = fmaxf(m, p[i]);
    red[t] = m; __syncthreads();
    for (int s = 128; s > 0; s >>= 1) { if (t < s) red[t] = fmaxf(red[t], red[t + s]); __syncthreads(); }
    m = red[0]; __syncthreads();

    float ssum = 0.f;
    for (int i = t; i < NNODES; i += 256) ssum += expf(p[i] - m);
    red[t] = ssum; __syncthreads();
    for (int s = 128; s > 0; s >>= 1) { if (t < s) red[t] += red[t + s]; __syncthreads(); }
    const float lse = m + logf(red[0]);

    for (int i = t; i < NNODES; i += 256) p[i] -= lse;
}

__global__ void alpha_k(const float* __restrict__ a, float* __restrict__ out)
{
    out[0] = 1.f / (1.f + expf(-a[0]));
}

extern "C" void kernel_launch(void* const* d_in, const int* in_sizes, int n_in,
                              void* d_out, int out_size, void* d_ws, size_t ws_size,
                              hipStream_t stream)
{
    const float* xn_in = (const float*)d_in[0];
    const float* xe_in = (const float*)d_in[1];
    const float* K1N   = (const float*)d_in[2];
    const float* K2N   = (const float*)d_in[3];
    const float* K1E   = (const float*)d_in[4];
    const float* K2E   = (const float*)d_in[5];
    const float* KNc   = (const float*)d_in[6];
    const float* KE1   = (const float*)d_in[7];
    const float* KE2   = (const float*)d_in[8];
    const float* KN1   = (const float*)d_in[9];
    const float* KN2   = (const float*)d_in[10];
    const float* l1w   = (const float*)d_in[11];
    const float* l1b   = (const float*)d_in[12];
    const float* l2w   = (const float*)d_in[13];
    const float* l2b   = (const float*)d_in[14];
    const float* alpha = (const float*)d_in[15];
    const int*   I     = (const int*)d_in[16];
    const int*   J     = (const int*)d_in[17];
    float* out = (float*)d_out;

    char* wsp = (char*)d_ws;
    auto alloc = [&](size_t bytes) -> char* {
        char* p = wsp; wsp += (bytes + 255) & ~(size_t)255; return p;
    };
    short* xn_buf = (short*)alloc((size_t)NNODES * 128 * 2);   // 2 MB
    short* xe_buf = (short*)alloc((size_t)NEDGES * 128 * 2);   // 16 MB
    short* t_e    = (short*)alloc((size_t)NEDGES * 256 * 2);   // 32 MB
    short* t_n    = (short*)alloc((size_t)NNODES * 256 * 2);   // 4 MB
    short* dxn_in = (short*)alloc((size_t)NNODES * 384 * 2);   // 6 MB
    short* xnc    = (short*)alloc((size_t)NNODES * 128 * 2);   // 2 MB
    short* x1     = (short*)alloc((size_t)NNODES * 256 * 2);   // 4 MB
    short* K2Nb   = (short*)alloc(128 * 128 * 2);
    short* K2Eb   = (short*)alloc(128 * 128 * 2);
    short* KNcb   = (short*)alloc(128 * 128 * 2);
    short* l1wb   = (short*)alloc(256 * 128 * 2);
    short* l2wb   = (short*)alloc((size_t)8192 * 256 * 2);     // 4.2 MB
    short* KE1b   = (short*)alloc((size_t)8 * 256 * 384 * 2);  // 1.6 MB
    short* KE2b   = (short*)alloc((size_t)8 * 128 * 256 * 2);
    short* KN1b   = (short*)alloc((size_t)8 * 256 * 384 * 2);
    short* KN2b   = (short*)alloc((size_t)8 * 128 * 256 * 2);
    int*   deg    = (int*)alloc((size_t)NNODES * 4);
    int*   rowp   = (int*)alloc((size_t)(NNODES + 8) * 4);
    int*   cur    = (int*)alloc((size_t)NNODES * 4);
    int*   ent    = (int*)alloc((size_t)2 * NEDGES * 4);
    double* sacc  = (double*)alloc(64);
    float*  smr   = (float*)alloc(64);

    const dim3 blk(256);
    auto cvt = [&](const float* src, short* dst, int n) {
        cvt_bf16_k<<<dim3((n + 255) / 256), blk, 0, stream>>>(src, dst, n);
    };

    // ---- weight conversion ----
    cvt(K2N, K2Nb, 128 * 128);
    cvt(K2E, K2Eb, 128 * 128);
    cvt(KNc, KNcb, 128 * 128);
    cvt(l1w, l1wb, 256 * 128);
    cvt(l2w, l2wb, 8192 * 256);
    cvt(KE1, KE1b, 8 * 256 * 384);
    cvt(KE2, KE2b, 8 * 128 * 256);
    cvt(KN1, KN1b, 8 * 256 * 384);
    cvt(KN2, KN2b, 8 * 128 * 256);

    // ---- CSR build ----
    hipMemsetAsync(deg, 0, (size_t)NNODES * 4, stream);
    csr_count_k<<<dim3(NEDGES / 256), blk, 0, stream>>>(I, J, deg);
    csr_scan_k<<<dim3(1), dim3(1024), 0, stream>>>(deg, rowp, cur);
    csr_fill_k<<<dim3(NEDGES / 256), blk, 0, stream>>>(I, J, cur, ent);

    // ---- opening: node ----
    hipMemsetAsync(sacc, 0, 16, stream);
    open_gemm_k<<<dim3(NNODES / 2), blk, 0, stream>>>(K1N, xn_in, xn_buf, 3, NNODES, sacc);
    finalize_stats_k<<<1, 1, 0, stream>>>(sacc, smr, 1.0 / (128.0 * NNODES));
    mfma_gemm_k<1, false, false, 0, false><<<dim3(NNODES / 128, 1), blk, 0, stream>>>(
        K2Nb, xn_buf, xn_buf, 128, 128, nullptr, nullptr, nullptr, nullptr,
        smr, nullptr, nullptr, 0.f, nullptr, 0);

    // ---- opening: edge ----
    hipMemsetAsync(sacc, 0, 16, stream);
    open_gemm_k<<<dim3(NEDGES / 2), blk, 0, stream>>>(K1E, xe_in, xe_buf, 16, NEDGES, sacc);
    finalize_stats_k<<<1, 1, 0, stream>>>(sacc, smr, 1.0 / (128.0 * NEDGES));
    mfma_gemm_k<1, false, false, 0, false><<<dim3(NEDGES / 128, 1), blk, 0, stream>>>(
        K2Eb, xe_buf, xe_buf, 128, 128, nullptr, nullptr, nullptr, nullptr,
        smr, nullptr, nullptr, 0.f, nullptr, 0);

    // ---- wave layers ----
    for (int l = 0; l < 8; ++l) {
        const short* ke1 = KE1b + (size_t)l * 256 * 384;
        const short* ke2 = KE2b + (size_t)l * 128 * 256;
        const short* kn1 = KN1b + (size_t)l * 256 * 384;
        const short* kn2 = KN2b + (size_t)l * 128 * 256;

        // edge: GEMM1 (fused concat-gather) + stats
        hipMemsetAsync(sacc, 0, 16, stream);
        mfma_gemm_k<2, true, false, 0, false><<<dim3(NEDGES / 128, 2), blk, 0, stream>>>(
            ke1, nullptr, t_e, 384, 256, xn_buf, xe_buf, I, J,
            nullptr, sacc, nullptr, 0.f, nullptr, 0);
        finalize_stats_k<<<1, 1, 0, stream>>>(sacc, smr, 1.0 / (256.0 * NEDGES));
        // edge: GEMM2 (LN+tanh on load, residual into xe_buf)
        mfma_gemm_k<1, false, true, 0, false><<<dim3(NEDGES / 128, 1), blk, 0, stream>>>(
            ke2, t_e, xe_buf, 256, 128, nullptr, nullptr, nullptr, nullptr,
            smr, nullptr, xe_buf, 0.1f, nullptr, 0);

        // node concat via CSR gather (no atomics)
        gather_node_k<<<dim3(NNODES), dim3(128), 0, stream>>>(xe_buf, xn_buf, rowp, ent, dxn_in);

        // node: GEMM1 + stats
        hipMemsetAsync(sacc, 0, 16, stream);
        mfma_gemm_k<0, true, false, 0, false><<<dim3(NNODES / 128, 2), blk, 0, stream>>>(
            kn1, dxn_in, t_n, 384, 256, nullptr, nullptr, nullptr, nullptr,
            nullptr, sacc, nullptr, 0.f, nullptr, 0);
        finalize_stats_k<<<1, 1, 0, stream>>>(sacc, smr, 1.0 / (256.0 * NNODES));
        // node: GEMM2
        mfma_gemm_k<1, false, true, 0, false><<<dim3(NNODES / 128, 1), blk, 0, stream>>>(
            kn2, t_n, xn_buf, 256, 128, nullptr, nullptr, nullptr, nullptr,
            smr, nullptr, xn_buf, 0.1f, nullptr, 0);
    }

    // ---- close + head ----
    mfma_gemm_k<0, false, false, 0, false><<<dim3(NNODES / 128, 1), blk, 0, stream>>>(
        KNcb, xn_buf, xnc, 128, 128, nullptr, nullptr, nullptr, nullptr,
        nullptr, nullptr, nullptr, 0.f, nullptr, 0);
    mfma_gemm_k<0, false, false, 2, false><<<dim3(NNODES / 128, 2), blk, 0, stream>>>(
        l1wb, xnc, x1, 128, 256, nullptr, nullptr, nullptr, nullptr,
        nullptr, nullptr, nullptr, 0.f, l1b, 0);
    mfma_gemm_k<0, false, false, 1, true><<<dim3(NNODES / 128, 8192 / 128), blk, 0, stream>>>(
        l2wb, x1, out, 256, 8192, nullptr, nullptr, nullptr, nullptr,
        nullptr, nullptr, nullptr, 0.f, l2b, 8192);

    log_softmax_k<<<dim3(NNODES), blk, 0, stream>>>(out);
    alpha_k<<<1, 1, 0, stream>>>(alpha, out + (size_t)NNODES * NNODES);
}

// Round 6
// 1599.465 us; speedup vs baseline: 13.2839x; 1.6613x over previous
//
#include <hip/hip_runtime.h>
#include <math.h>

#define NNODES 8192
#define NEDGES 65536
#define NSLOTS 64

typedef __attribute__((ext_vector_type(8))) short bf16x8;
typedef __attribute__((ext_vector_type(4))) float f32x4;

__device__ __forceinline__ float b2f(short s) {
    unsigned int u = ((unsigned int)(unsigned short)s) << 16;
    float f; __builtin_memcpy(&f, &u, 4); return f;
}
__device__ __forceinline__ short f2b(float f) {
    unsigned int u; __builtin_memcpy(&u, &f, 4);
    u = (u + 0x7fffu + ((u >> 16) & 1u)) >> 16;
    return (short)u;
}

__device__ __forceinline__ void async_copy16(const void* g, void* l) {
    __builtin_amdgcn_global_load_lds(
        (const __attribute__((address_space(1))) void*)g,
        (__attribute__((address_space(3))) void*)l, 16, 0, 0);
}

// ---------------------------------------------------------------------------
// MFMA GEMM:  Y[m][o] = sum_c X[m][c] * W[o][c]   (+ epilogue)
// XMODE: 0 = direct [M][C] via global_load_lds; 1 = + tanh((x-mean)*rstd) on
// load; 2 = edge concat [0.5*(xn[I]+xn[J]) | xe | xn[I]-xn[J]], C=384.
// STATS: striped f32 slot atomics (NSLOTS pairs) for next layer's global LN.
// LDS chunk swizzle: physical chunk p of row r holds logical K-chunk (p-(r>>1))&3
// ---------------------------------------------------------------------------
template<int XMODE, bool STATS, bool RESID, int EPI, bool OUTF32>
__global__ __launch_bounds__(256)
void mfma_gemm_k(const short* __restrict__ Wg, const short* __restrict__ Xg,
                 void* __restrict__ Yv, int C, int ldY,
                 const short* __restrict__ xnB, const short* __restrict__ xeB,
                 const int* __restrict__ Iidx, const int* __restrict__ Jidx,
                 const float* __restrict__ mr, float* __restrict__ stat_slots,
                 const short* __restrict__ Rres, float Hc,
                 const float* __restrict__ bias, int ldOut)
{
    __shared__ __attribute__((aligned(16))) short Xs[128 * 32];
    __shared__ __attribute__((aligned(16))) short Ws[128 * 32];
    __shared__ float rs[256], rq[256];

    const int t    = threadIdx.x;
    const int m0   = blockIdx.x * 128;
    const int o0   = blockIdx.y * 128;
    const int wave = t >> 6, lane = t & 63;
    const int wm   = wave >> 1, wn = wave & 1;
    const int lr   = lane & 15, kg = lane >> 4;

    float mean = 0.f, rstd = 1.f;
    if (XMODE == 1) { mean = mr[0]; rstd = mr[1]; }

    f32x4 acc[4][4];
    #pragma unroll
    for (int i = 0; i < 4; ++i)
        #pragma unroll
        for (int n = 0; n < 4; ++n)
            acc[i][n] = (f32x4){0.f, 0.f, 0.f, 0.f};

    for (int k0 = 0; k0 < C; k0 += 32) {
        // ---- stage W tile (always direct async copy) ----
        #pragma unroll
        for (int h = 0; h < 2; ++h) {
            int s  = t + h * 256;
            int r  = s >> 2;
            int kc = ((s & 3) - (r >> 1)) & 3;
            async_copy16(Wg + (size_t)(o0 + r) * C + k0 + kc * 8,
                         (char*)Ws + h * 4096 + wave * 1024);
        }
        // ---- stage X tile ----
        if (XMODE == 0) {
            #pragma unroll
            for (int h = 0; h < 2; ++h) {
                int s  = t + h * 256;
                int r  = s >> 2;
                int kc = ((s & 3) - (r >> 1)) & 3;
                async_copy16(Xg + (size_t)(m0 + r) * C + k0 + kc * 8,
                             (char*)Xs + h * 4096 + wave * 1024);
            }
        } else {
            #pragma unroll
            for (int h = 0; h < 2; ++h) {
                int s = t + h * 256;
                int r = s >> 2, kc = s & 3;
                int p = (kc + (r >> 1)) & 3;
                int c0 = k0 + kc * 8;
                bf16x8 o8;
                if (XMODE == 1) {
                    bf16x8 x = *(const bf16x8*)(Xg + (size_t)(m0 + r) * C + c0);
                    #pragma unroll
                    for (int j = 0; j < 8; ++j) {
                        float f = b2f(x[j]);
                        o8[j] = f2b(tanhf((f - mean) * rstd));
                    }
                } else { // XMODE == 2, C = 384
                    int e = m0 + r;
                    if (c0 < 128) {
                        bf16x8 xa = *(const bf16x8*)(xnB + (size_t)Iidx[e] * 128 + c0);
                        bf16x8 xb = *(const bf16x8*)(xnB + (size_t)Jidx[e] * 128 + c0);
                        #pragma unroll
                        for (int j = 0; j < 8; ++j) o8[j] = f2b(0.5f * (b2f(xa[j]) + b2f(xb[j])));
                    } else if (c0 < 256) {
                        o8 = *(const bf16x8*)(xeB + (size_t)e * 128 + (c0 - 128));
                    } else {
                        bf16x8 xa = *(const bf16x8*)(xnB + (size_t)Iidx[e] * 128 + (c0 - 256));
                        bf16x8 xb = *(const bf16x8*)(xnB + (size_t)Jidx[e] * 128 + (c0 - 256));
                        #pragma unroll
                        for (int j = 0; j < 8; ++j) o8[j] = f2b(b2f(xa[j]) - b2f(xb[j]));
                    }
                }
                *(bf16x8*)&Xs[r * 32 + p * 8] = o8;
            }
        }
        __syncthreads();   // drains vmcnt (global_load_lds) / lgkmcnt (ds_write)

        bf16x8 a[4], b[4];
        #pragma unroll
        for (int i = 0; i < 4; ++i) {
            int ra = wm * 64 + i * 16 + lr;
            int pa = (kg + (ra >> 1)) & 3;
            a[i] = *(const bf16x8*)&Xs[ra * 32 + pa * 8];
            int rb = wn * 64 + i * 16 + lr;
            int pb = (kg + (rb >> 1)) & 3;
            b[i] = *(const bf16x8*)&Ws[rb * 32 + pb * 8];
        }
        #pragma unroll
        for (int i = 0; i < 4; ++i)
            #pragma unroll
            for (int n = 0; n < 4; ++n)
                acc[i][n] = __builtin_amdgcn_mfma_f32_16x16x32_bf16(a[i], b[n], acc[i][n], 0, 0, 0);
        __syncthreads();
    }

    // ---- epilogue ----
    float lsum = 0.f, lsq = 0.f;
    #pragma unroll
    for (int i = 0; i < 4; ++i) {
        #pragma unroll
        for (int n = 0; n < 4; ++n) {
            #pragma unroll
            for (int r = 0; r < 4; ++r) {
                float v = acc[i][n][r];
                const int m = m0 + wm * 64 + i * 16 + kg * 4 + r;
                const int o = o0 + wn * 64 + n * 16 + lr;
                if (RESID)    v = b2f(Rres[(size_t)m * ldY + o]) + Hc * v;
                if (EPI >= 1) v += bias[o];
                if (EPI == 2) v = v > 0.f ? v : expf(v) - 1.f;
                if (OUTF32) ((float*)Yv)[(size_t)m * ldOut + o] = v;
                else        ((short*)Yv)[(size_t)m * ldY + o] = f2b(v);
                if (STATS) { lsum += v; lsq += v * v; }
            }
        }
    }

    if (STATS) {
        rs[t] = lsum; rq[t] = lsq;
        __syncthreads();
        for (int s = 128; s > 0; s >>= 1) {
            if (t < s) { rs[t] += rs[t + s]; rq[t] += rq[t + s]; }
            __syncthreads();
        }
        if (t == 0) {
            int slot = (blockIdx.x + blockIdx.y * gridDim.x) & (NSLOTS - 1);
            atomicAdd(&stat_slots[slot * 2], rs[0]);
            atomicAdd(&stat_slots[slot * 2 + 1], rq[0]);
        }
    }
}

// Opening conv1 (tiny C): Y[m][o] bf16 from W[128][C] f32, X[C][M] f32, + stats.
// Block: 256 threads = 128 o x 2 m-halves; each thread does TM m-columns.
template<int C, int TM>
__global__ __launch_bounds__(256)
void open_gemm_k(const float* __restrict__ W, const float* __restrict__ X,
                 short* __restrict__ Y, int M, float* __restrict__ stat_slots)
{
    __shared__ float Xt[C][2 * TM];
    __shared__ float rs[256], rq[256];
    const int t = threadIdx.x;
    const int o = t & 127, h = t >> 7;
    const int mbase = blockIdx.x * 2 * TM;

    for (int idx = t; idx < C * 2 * TM; idx += 256) {
        int c = idx / (2 * TM), mm = idx % (2 * TM);
        Xt[c][mm] = X[(size_t)c * M + mbase + mm];
    }
    float w[C];
    #pragma unroll
    for (int c = 0; c < C; ++c) w[c] = W[o * C + c];
    __syncthreads();

    float lsum = 0.f, lsq = 0.f;
    #pragma unroll
    for (int i = 0; i < TM; ++i) {
        int mm = h * TM + i;
        float acc = 0.f;
        #pragma unroll
        for (int c = 0; c < C; ++c) acc += w[c] * Xt[c][mm];
        Y[(size_t)(mbase + mm) * 128 + o] = f2b(acc);
        lsum += acc; lsq += acc * acc;
    }
    rs[t] = lsum; rq[t] = lsq;
    __syncthreads();
    for (int s = 128; s > 0; s >>= 1) {
        if (t < s) { rs[t] += rs[t + s]; rq[t] += rq[t + s]; }
        __syncthreads();
    }
    if (t == 0) {
        int slot = blockIdx.x & (NSLOTS - 1);
        atomicAdd(&stat_slots[slot * 2], rs[0]);
        atomicAdd(&stat_slots[slot * 2 + 1], rq[0]);
    }
}

__global__ void finalize_stats_k(const float* __restrict__ slots, float* __restrict__ mr, double invCnt)
{
    double s = 0.0, q = 0.0;
    for (int i = 0; i < NSLOTS; ++i) { s += (double)slots[i * 2]; q += (double)slots[i * 2 + 1]; }
    double mean = s * invCnt;
    double var  = q * invCnt - mean * mean;
    mr[0] = (float)mean;
    mr[1] = (float)(1.0 / sqrt(var + 1e-5));
}

__global__ void cvt_bf16_k(const float* __restrict__ in, short* __restrict__ out, int n)
{
    int i = blockIdx.x * 256 + threadIdx.x;
    if (i < n) out[i] = f2b(in[i]);
}

// ---------------- CSR build ------------------------------------------------
__global__ __launch_bounds__(256)
void csr_count_k(const int* __restrict__ I, const int* __restrict__ J, int* __restrict__ deg)
{
    int e = blockIdx.x * 256 + threadIdx.x;
    atomicAdd(&deg[I[e]], 1);
    atomicAdd(&deg[J[e]], 1);
}

__global__ __launch_bounds__(1024)
void csr_scan_k(const int* __restrict__ deg, int* __restrict__ rowp, int* __restrict__ cur)
{
    __shared__ int part[1024];
    const int t = threadIdx.x;
    const int base = t * 8;
    int s = 0;
    #pragma unroll
    for (int i = 0; i < 8; ++i) s += deg[base + i];
    part[t] = s; __syncthreads();
    for (int off = 1; off < 1024; off <<= 1) {
        int v = (t >= off) ? part[t - off] : 0;
        __syncthreads();
        part[t] += v;
        __syncthreads();
    }
    int run = (t == 0) ? 0 : part[t - 1];
    #pragma unroll
    for (int i = 0; i < 8; ++i) {
        rowp[base + i] = run; cur[base + i] = run;
        run += deg[base + i];
    }
    if (t == 1023) rowp[8192] = run;
}

__global__ __launch_bounds__(256)
void csr_fill_k(const int* __restrict__ I, const int* __restrict__ J,
                int* __restrict__ cur, int* __restrict__ ent)
{
    int e = blockIdx.x * 256 + threadIdx.x;
    int p = atomicAdd(&cur[I[e]], 1); ent[p] = e;
    int q = atomicAdd(&cur[J[e]], 1); ent[q] = e | (int)0x80000000;
}

// node concat: dxn[n][0:128]=edge_ave, [128:256]=edge_div, [256:384]=xn
__global__ __launch_bounds__(128)
void gather_node_k(const short* __restrict__ xe, const short* __restrict__ xn,
                   const int* __restrict__ rowp, const int* __restrict__ ent,
                   short* __restrict__ dxn)
{
    const int n = blockIdx.x;
    const int c = threadIdx.x;
    const int b = rowp[n], e2 = rowp[n + 1];
    float ave = 0.f, dv = 0.f;
    for (int k = b; k < e2; ++k) {
        int v = ent[k];
        int e = v & 0x7fffffff;
        float x = b2f(xe[(size_t)e * 128 + c]);
        ave += x;
        dv  += (v < 0) ? -x : x;
    }
    size_t base = (size_t)n * 384;
    dxn[base + c]       = f2b(0.5f * ave);
    dxn[base + 128 + c] = f2b(dv);
    dxn[base + 256 + c] = xn[(size_t)n * 128 + c];
}

// online max+sum pass, then subtract pass; float4 loads
__global__ __launch_bounds__(256)
void log_softmax_k(float* __restrict__ y)
{
    const int row = blockIdx.x;
    float* p = y + (size_t)row * NNODES;
    __shared__ float redm[256], reds[256];
    const int t = threadIdx.x;

    float m = -INFINITY, s = 0.f;
    for (int i = t; i < NNODES / 4; i += 256) {
        f32x4 v = ((const f32x4*)p)[i];
        #pragma unroll
        for (int j = 0; j < 4; ++j) {
            float x = v[j];
            if (x > m) { s = s * __expf(m - x) + 1.f; m = x; }
            else       { s += __expf(x - m); }
        }
    }
    redm[t] = m; reds[t] = s; __syncthreads();
    for (int st = 128; st > 0; st >>= 1) {
        if (t < st) {
            float m2 = redm[t + st], s2 = reds[t + st];
            float mm = fmaxf(redm[t], m2);
            reds[t] = reds[t] * __expf(redm[t] - mm) + s2 * __expf(m2 - mm);
            redm[t] = mm;
        }
        __syncthreads();
    }
    const float lse = redm[0] + logf(reds[0]);

    for (int i = t; i < NNODES / 4; i += 256) {
        f32x4 v = ((const f32x4*)p)[i];
        #pragma unroll
        for (int j = 0; j < 4; ++j) v[j] -= lse;
        ((f32x4*)p)[i] = v;
    }
}

__global__ void alpha_k(const float* __restrict__ a, float* __restrict__ out)
{
    out[0] = 1.f / (1.f + expf(-a[0]));
}

extern "C" void kernel_launch(void* const* d_in, const int* in_sizes, int n_in,
                              void* d_out, int out_size, void* d_ws, size_t ws_size,
                              hipStream_t stream)
{
    const float* xn_in = (const float*)d_in[0];
    const float* xe_in = (const float*)d_in[1];
    const float* K1N   = (const float*)d_in[2];
    const float* K2N   = (const float*)d_in[3];
    const float* K1E   = (const float*)d_in[4];
    const float* K2E   = (const float*)d_in[5];
    const float* KNc   = (const float*)d_in[6];
    const float* KE1   = (const float*)d_in[7];
    const float* KE2   = (const float*)d_in[8];
    const float* KN1   = (const float*)d_in[9];
    const float* KN2   = (const float*)d_in[10];
    const float* l1w   = (const float*)d_in[11];
    const float* l1b   = (const float*)d_in[12];
    const float* l2w   = (const float*)d_in[13];
    const float* l2b   = (const float*)d_in[14];
    const float* alpha = (const float*)d_in[15];
    const int*   I     = (const int*)d_in[16];
    const int*   J     = (const int*)d_in[17];
    float* out = (float*)d_out;

    char* wsp = (char*)d_ws;
    auto alloc = [&](size_t bytes) -> char* {
        char* p = wsp; wsp += (bytes + 255) & ~(size_t)255; return p;
    };
    short* xn_buf = (short*)alloc((size_t)NNODES * 128 * 2);   // 2 MB
    short* xe_buf = (short*)alloc((size_t)NEDGES * 128 * 2);   // 16 MB
    short* t_e    = (short*)alloc((size_t)NEDGES * 256 * 2);   // 32 MB
    short* t_n    = (short*)alloc((size_t)NNODES * 256 * 2);   // 4 MB
    short* dxn_in = (short*)alloc((size_t)NNODES * 384 * 2);   // 6 MB
    short* xnc    = (short*)alloc((size_t)NNODES * 128 * 2);   // 2 MB
    short* x1     = (short*)alloc((size_t)NNODES * 256 * 2);   // 4 MB
    short* K2Nb   = (short*)alloc(128 * 128 * 2);
    short* K2Eb   = (short*)alloc(128 * 128 * 2);
    short* KNcb   = (short*)alloc(128 * 128 * 2);
    short* l1wb   = (short*)alloc(256 * 128 * 2);
    short* l2wb   = (short*)alloc((size_t)8192 * 256 * 2);     // 4.2 MB
    short* KE1b   = (short*)alloc((size_t)8 * 256 * 384 * 2);  // 1.6 MB
    short* KE2b   = (short*)alloc((size_t)8 * 128 * 256 * 2);
    short* KN1b   = (short*)alloc((size_t)8 * 256 * 384 * 2);
    short* KN2b   = (short*)alloc((size_t)8 * 128 * 256 * 2);
    int*   deg    = (int*)alloc((size_t)NNODES * 4);
    int*   rowp   = (int*)alloc((size_t)(NNODES + 8) * 4);
    int*   cur    = (int*)alloc((size_t)NNODES * 4);
    int*   ent    = (int*)alloc((size_t)2 * NEDGES * 4);
    float* sacc   = (float*)alloc(NSLOTS * 2 * 4);
    float* smr    = (float*)alloc(64);

    const dim3 blk(256);
    auto cvt = [&](const float* src, short* dst, int n) {
        cvt_bf16_k<<<dim3((n + 255) / 256), blk, 0, stream>>>(src, dst, n);
    };
    auto zero_slots = [&]() {
        hipMemsetAsync(sacc, 0, NSLOTS * 2 * 4, stream);
    };

    // ---- weight conversion ----
    cvt(K2N, K2Nb, 128 * 128);
    cvt(K2E, K2Eb, 128 * 128);
    cvt(KNc, KNcb, 128 * 128);
    cvt(l1w, l1wb, 256 * 128);
    cvt(l2w, l2wb, 8192 * 256);
    cvt(KE1, KE1b, 8 * 256 * 384);
    cvt(KE2, KE2b, 8 * 128 * 256);
    cvt(KN1, KN1b, 8 * 256 * 384);
    cvt(KN2, KN2b, 8 * 128 * 256);

    // ---- CSR build ----
    hipMemsetAsync(deg, 0, (size_t)NNODES * 4, stream);
    csr_count_k<<<dim3(NEDGES / 256), blk, 0, stream>>>(I, J, deg);
    csr_scan_k<<<dim3(1), dim3(1024), 0, stream>>>(deg, rowp, cur);
    csr_fill_k<<<dim3(NEDGES / 256), blk, 0, stream>>>(I, J, cur, ent);

    // ---- opening: node ----
    zero_slots();
    open_gemm_k<3, 16><<<dim3(NNODES / 32), blk, 0, stream>>>(K1N, xn_in, xn_buf, NNODES, sacc);
    finalize_stats_k<<<1, 1, 0, stream>>>(sacc, smr, 1.0 / (128.0 * NNODES));
    mfma_gemm_k<1, false, false, 0, false><<<dim3(NNODES / 128, 1), blk, 0, stream>>>(
        K2Nb, xn_buf, xn_buf, 128, 128, nullptr, nullptr, nullptr, nullptr,
        smr, nullptr, nullptr, 0.f, nullptr, 0);

    // ---- opening: edge ----
    zero_slots();
    open_gemm_k<16, 16><<<dim3(NEDGES / 32), blk, 0, stream>>>(K1E, xe_in, xe_buf, NEDGES, sacc);
    finalize_stats_k<<<1, 1, 0, stream>>>(sacc, smr, 1.0 / (128.0 * NEDGES));
    mfma_gemm_k<1, false, false, 0, false><<<dim3(NEDGES / 128, 1), blk, 0, stream>>>(
        K2Eb, xe_buf, xe_buf, 128, 128, nullptr, nullptr, nullptr, nullptr,
        smr, nullptr, nullptr, 0.f, nullptr, 0);

    // ---- wave layers ----
    for (int l = 0; l < 8; ++l) {
        const short* ke1 = KE1b + (size_t)l * 256 * 384;
        const short* ke2 = KE2b + (size_t)l * 128 * 256;
        const short* kn1 = KN1b + (size_t)l * 256 * 384;
        const short* kn2 = KN2b + (size_t)l * 128 * 256;

        // edge: GEMM1 (fused concat-gather) + stats
        zero_slots();
        mfma_gemm_k<2, true, false, 0, false><<<dim3(NEDGES / 128, 2), blk, 0, stream>>>(
            ke1, nullptr, t_e, 384, 256, xn_buf, xe_buf, I, J,
            nullptr, sacc, nullptr, 0.f, nullptr, 0);
        finalize_stats_k<<<1, 1, 0, stream>>>(sacc, smr, 1.0 / (256.0 * NEDGES));
        // edge: GEMM2 (LN+tanh on load, residual into xe_buf)
        mfma_gemm_k<1, false, true, 0, false><<<dim3(NEDGES / 128, 1), blk, 0, stream>>>(
            ke2, t_e, xe_buf, 256, 128, nullptr, nullptr, nullptr, nullptr,
            smr, nullptr, xe_buf, 0.1f, nullptr, 0);

        // node concat via CSR gather (no atomics)
        gather_node_k<<<dim3(NNODES), dim3(128), 0, stream>>>(xe_buf, xn_buf, rowp, ent, dxn_in);

        // node: GEMM1 + stats
        zero_slots();
        mfma_gemm_k<0, true, false, 0, false><<<dim3(NNODES / 128, 2), blk, 0, stream>>>(
            kn1, dxn_in, t_n, 384, 256, nullptr, nullptr, nullptr, nullptr,
            nullptr, sacc, nullptr, 0.f, nullptr, 0);
        finalize_stats_k<<<1, 1, 0, stream>>>(sacc, smr, 1.0 / (256.0 * NNODES));
        // node: GEMM2
        mfma_gemm_k<1, false, true, 0, false><<<dim3(NNODES / 128, 1), blk, 0, stream>>>(
            kn2, t_n, xn_buf, 256, 128, nullptr, nullptr, nullptr, nullptr,
            smr, nullptr, xn_buf, 0.1f, nullptr, 0);
    }

    // ---- close + head ----
    mfma_gemm_k<0, false, false, 0, false><<<dim3(NNODES / 128, 1), blk, 0, stream>>>(
        KNcb, xn_buf, xnc, 128, 128, nullptr, nullptr, nullptr, nullptr,
        nullptr, nullptr, nullptr, 0.f, nullptr, 0);
    mfma_gemm_k<0, false, false, 2, false><<<dim3(NNODES / 128, 2), blk, 0, stream>>>(
        l1wb, xnc, x1, 128, 256, nullptr, nullptr, nullptr, nullptr,
        nullptr, nullptr, nullptr, 0.f, l1b, 0);
    mfma_gemm_k<0, false, false, 1, true><<<dim3(NNODES / 128, 8192 / 128), blk, 0, stream>>>(
        l2wb, x1, out, 256, 8192, nullptr, nullptr, nullptr, nullptr,
        nullptr, nullptr, nullptr, 0.f, l2b, 8192);

    log_softmax_k<<<dim3(NNODES), blk, 0, stream>>>(out);
    alpha_k<<<1, 1, 0, stream>>>(alpha, out + (size_t)NNODES * NNODES);
}

// Round 8
// 1535.432 us; speedup vs baseline: 13.8379x; 1.0417x over previous
//
#include <hip/hip_runtime.h>
#include <math.h>

#define NNODES 8192
#define NEDGES 65536
#define NSLOTS 64

typedef __attribute__((ext_vector_type(8))) short bf16x8;
typedef __attribute__((ext_vector_type(4))) float f32x4;

__device__ __forceinline__ float b2f(short s) {
    unsigned int u = ((unsigned int)(unsigned short)s) << 16;
    float f; __builtin_memcpy(&f, &u, 4); return f;
}
__device__ __forceinline__ short f2b(float f) {
    unsigned int u; __builtin_memcpy(&u, &f, 4);
    u = (u + 0x7fffu + ((u >> 16) & 1u)) >> 16;
    return (short)u;
}

__device__ __forceinline__ void async_copy16(const void* g, void* l) {
    __builtin_amdgcn_global_load_lds(
        (const __attribute__((address_space(1))) void*)g,
        (__attribute__((address_space(3))) void*)l, 16, 0, 0);
}

// ---------------------------------------------------------------------------
// MFMA GEMM:  Y[m][o] = sum_c X[m][c] * W[o][c]   (+ epilogue)
// XMODE: 0 = direct [M][C] via global_load_lds; 1 = + tanh((x-mean)*rstd) on
// load (mean/rstd derived in-block from ln_slots); 2 = edge concat
// [0.5*(xn[I]+xn[J]) | xe | xn[I]-xn[J]], C=384.
// STATS: striped f32 slot atomics (NSLOTS pairs) for the NEXT layer's LN.
// LDS chunk swizzle: physical chunk p of row r holds logical K-chunk (p-(r>>1))&3
// ---------------------------------------------------------------------------
template<int XMODE, bool STATS, bool RESID, int EPI, bool OUTF32>
__global__ __launch_bounds__(256)
void mfma_gemm_k(const short* __restrict__ Wg, const short* __restrict__ Xg,
                 void* __restrict__ Yv, int C, int ldY,
                 const short* __restrict__ xnB, const short* __restrict__ xeB,
                 const int* __restrict__ Iidx, const int* __restrict__ Jidx,
                 const float* __restrict__ ln_slots, float invCnt,
                 float* __restrict__ stat_slots,
                 const short* __restrict__ Rres, float Hc,
                 const float* __restrict__ bias, int ldOut)
{
    __shared__ __attribute__((aligned(16))) short Xs[128 * 32];
    __shared__ __attribute__((aligned(16))) short Ws[128 * 32];
    __shared__ float rs[256], rq[256];

    const int t    = threadIdx.x;
    const int m0   = blockIdx.x * 128;
    const int o0   = blockIdx.y * 128;
    const int wave = t >> 6, lane = t & 63;
    const int wm   = wave >> 1, wn = wave & 1;
    const int lr   = lane & 15, kg = lane >> 4;

    float mean = 0.f, rstd = 1.f;
    if (XMODE == 1) {
        // in-block LN finalize: reduce 64 striped slot pairs
        if (t < NSLOTS) { rs[t] = ln_slots[2 * t]; rq[t] = ln_slots[2 * t + 1]; }
        __syncthreads();
        if (t == 0) {
            double s = 0.0, q = 0.0;
            for (int i = 0; i < NSLOTS; ++i) { s += (double)rs[i]; q += (double)rq[i]; }
            double mn = s * (double)invCnt;
            double var = q * (double)invCnt - mn * mn;
            rs[0] = (float)mn;
            rq[0] = (float)(1.0 / sqrt(var + 1e-5));
        }
        __syncthreads();
        mean = rs[0]; rstd = rq[0];
        __syncthreads();
    }

    f32x4 acc[4][4];
    #pragma unroll
    for (int i = 0; i < 4; ++i)
        #pragma unroll
        for (int n = 0; n < 4; ++n)
            acc[i][n] = (f32x4){0.f, 0.f, 0.f, 0.f};

    for (int k0 = 0; k0 < C; k0 += 32) {
        // ---- stage W tile (always direct async copy) ----
        #pragma unroll
        for (int h = 0; h < 2; ++h) {
            int s  = t + h * 256;
            int r  = s >> 2;
            int kc = ((s & 3) - (r >> 1)) & 3;
            async_copy16(Wg + (size_t)(o0 + r) * C + k0 + kc * 8,
                         (char*)Ws + h * 4096 + wave * 1024);
        }
        // ---- stage X tile ----
        if (XMODE == 0) {
            #pragma unroll
            for (int h = 0; h < 2; ++h) {
                int s  = t + h * 256;
                int r  = s >> 2;
                int kc = ((s & 3) - (r >> 1)) & 3;
                async_copy16(Xg + (size_t)(m0 + r) * C + k0 + kc * 8,
                             (char*)Xs + h * 4096 + wave * 1024);
            }
        } else {
            #pragma unroll
            for (int h = 0; h < 2; ++h) {
                int s = t + h * 256;
                int r = s >> 2, kc = s & 3;
                int p = (kc + (r >> 1)) & 3;
                int c0 = k0 + kc * 8;
                bf16x8 o8;
                if (XMODE == 1) {
                    bf16x8 x = *(const bf16x8*)(Xg + (size_t)(m0 + r) * C + c0);
                    #pragma unroll
                    for (int j = 0; j < 8; ++j) {
                        float f = b2f(x[j]);
                        o8[j] = f2b(tanhf((f - mean) * rstd));
                    }
                } else { // XMODE == 2, C = 384
                    int e = m0 + r;
                    if (c0 < 128) {
                        bf16x8 xa = *(const bf16x8*)(xnB + (size_t)Iidx[e] * 128 + c0);
                        bf16x8 xb = *(const bf16x8*)(xnB + (size_t)Jidx[e] * 128 + c0);
                        #pragma unroll
                        for (int j = 0; j < 8; ++j) o8[j] = f2b(0.5f * (b2f(xa[j]) + b2f(xb[j])));
                    } else if (c0 < 256) {
                        o8 = *(const bf16x8*)(xeB + (size_t)e * 128 + (c0 - 128));
                    } else {
                        bf16x8 xa = *(const bf16x8*)(xnB + (size_t)Iidx[e] * 128 + (c0 - 256));
                        bf16x8 xb = *(const bf16x8*)(xnB + (size_t)Jidx[e] * 128 + (c0 - 256));
                        #pragma unroll
                        for (int j = 0; j < 8; ++j) o8[j] = f2b(b2f(xa[j]) - b2f(xb[j]));
                    }
                }
                *(bf16x8*)&Xs[r * 32 + p * 8] = o8;
            }
        }
        __syncthreads();   // drains vmcnt (global_load_lds) / lgkmcnt (ds_write)

        bf16x8 a[4], b[4];
        #pragma unroll
        for (int i = 0; i < 4; ++i) {
            int ra = wm * 64 + i * 16 + lr;
            int pa = (kg + (ra >> 1)) & 3;
            a[i] = *(const bf16x8*)&Xs[ra * 32 + pa * 8];
            int rb = wn * 64 + i * 16 + lr;
            int pb = (kg + (rb >> 1)) & 3;
            b[i] = *(const bf16x8*)&Ws[rb * 32 + pb * 8];
        }
        #pragma unroll
        for (int i = 0; i < 4; ++i)
            #pragma unroll
            for (int n = 0; n < 4; ++n)
                acc[i][n] = __builtin_amdgcn_mfma_f32_16x16x32_bf16(a[i], b[n], acc[i][n], 0, 0, 0);
        __syncthreads();
    }

    // ---- epilogue ----
    float lsum = 0.f, lsq = 0.f;
    #pragma unroll
    for (int i = 0; i < 4; ++i) {
        #pragma unroll
        for (int n = 0; n < 4; ++n) {
            #pragma unroll
            for (int r = 0; r < 4; ++r) {
                float v = acc[i][n][r];
                const int m = m0 + wm * 64 + i * 16 + kg * 4 + r;
                const int o = o0 + wn * 64 + n * 16 + lr;
                if (RESID)    v = b2f(Rres[(size_t)m * ldY + o]) + Hc * v;
                if (EPI >= 1) v += bias[o];
                if (EPI == 2) v = v > 0.f ? v : expf(v) - 1.f;
                if (OUTF32) ((float*)Yv)[(size_t)m * ldOut + o] = v;
                else        ((short*)Yv)[(size_t)m * ldY + o] = f2b(v);
                if (STATS) { lsum += v; lsq += v * v; }
            }
        }
    }

    if (STATS) {
        rs[t] = lsum; rq[t] = lsq;
        __syncthreads();
        for (int s = 128; s > 0; s >>= 1) {
            if (t < s) { rs[t] += rs[t + s]; rq[t] += rq[t + s]; }
            __syncthreads();
        }
        if (t == 0) {
            int slot = (blockIdx.x + blockIdx.y * gridDim.x) & (NSLOTS - 1);
            atomicAdd(&stat_slots[slot * 2], rs[0]);
            atomicAdd(&stat_slots[slot * 2 + 1], rq[0]);
        }
    }
}

// Opening conv1 (tiny C): Y[m][o] bf16 from W[128][C] f32, X[C][M] f32, + stats.
template<int C, int TM>
__global__ __launch_bounds__(256)
void open_gemm_k(const float* __restrict__ W, const float* __restrict__ X,
                 short* __restrict__ Y, int M, float* __restrict__ stat_slots)
{
    __shared__ float Xt[C][2 * TM];
    __shared__ float rs[256], rq[256];
    const int t = threadIdx.x;
    const int o = t & 127, h = t >> 7;
    const int mbase = blockIdx.x * 2 * TM;

    for (int idx = t; idx < C * 2 * TM; idx += 256) {
        int c = idx / (2 * TM), mm = idx % (2 * TM);
        Xt[c][mm] = X[(size_t)c * M + mbase + mm];
    }
    float w[C];
    #pragma unroll
    for (int c = 0; c < C; ++c) w[c] = W[o * C + c];
    __syncthreads();

    float lsum = 0.f, lsq = 0.f;
    #pragma unroll
    for (int i = 0; i < TM; ++i) {
        int mm = h * TM + i;
        float acc = 0.f;
        #pragma unroll
        for (int c = 0; c < C; ++c) acc += w[c] * Xt[c][mm];
        Y[(size_t)(mbase + mm) * 128 + o] = f2b(acc);
        lsum += acc; lsq += acc * acc;
    }
    rs[t] = lsum; rq[t] = lsq;
    __syncthreads();
    for (int s = 128; s > 0; s >>= 1) {
        if (t < s) { rs[t] += rs[t + s]; rq[t] += rq[t + s]; }
        __syncthreads();
    }
    if (t == 0) {
        int slot = blockIdx.x & (NSLOTS - 1);
        atomicAdd(&stat_slots[slot * 2], rs[0]);
        atomicAdd(&stat_slots[slot * 2 + 1], rq[0]);
    }
}

// ---- single fused weight-conversion kernel (9 segments) ----
struct CvtJobs {
    const float* src[9];
    short* dst[9];
    int n[9];
};

__global__ __launch_bounds__(256)
void cvt_all_k(CvtJobs jobs)
{
    const int stride = gridDim.x * 256;
    #pragma unroll
    for (int s = 0; s < 9; ++s) {
        const float* src = jobs.src[s];
        short* dst = jobs.dst[s];
        const int n = jobs.n[s];
        for (int i = blockIdx.x * 256 + threadIdx.x; i < n; i += stride)
            dst[i] = f2b(src[i]);
    }
}

// ---------------- CSR build ------------------------------------------------
__global__ __launch_bounds__(256)
void csr_count_k(const int* __restrict__ I, const int* __restrict__ J, int* __restrict__ deg)
{
    int e = blockIdx.x * 256 + threadIdx.x;
    atomicAdd(&deg[I[e]], 1);
    atomicAdd(&deg[J[e]], 1);
}

__global__ __launch_bounds__(1024)
void csr_scan_k(const int* __restrict__ deg, int* __restrict__ rowp, int* __restrict__ cur)
{
    __shared__ int part[1024];
    const int t = threadIdx.x;
    const int base = t * 8;
    int s = 0;
    #pragma unroll
    for (int i = 0; i < 8; ++i) s += deg[base + i];
    part[t] = s; __syncthreads();
    for (int off = 1; off < 1024; off <<= 1) {
        int v = (t >= off) ? part[t - off] : 0;
        __syncthreads();
        part[t] += v;
        __syncthreads();
    }
    int run = (t == 0) ? 0 : part[t - 1];
    #pragma unroll
    for (int i = 0; i < 8; ++i) {
        rowp[base + i] = run; cur[base + i] = run;
        run += deg[base + i];
    }
    if (t == 1023) rowp[8192] = run;
}

__global__ __launch_bounds__(256)
void csr_fill_k(const int* __restrict__ I, const int* __restrict__ J,
                int* __restrict__ cur, int* __restrict__ ent)
{
    int e = blockIdx.x * 256 + threadIdx.x;
    int p = atomicAdd(&cur[I[e]], 1); ent[p] = e;
    int q = atomicAdd(&cur[J[e]], 1); ent[q] = e | (int)0x80000000;
}

// node concat: dxn[n][0:128]=edge_ave, [128:256]=edge_div, [256:384]=xn
__global__ __launch_bounds__(128)
void gather_node_k(const short* __restrict__ xe, const short* __restrict__ xn,
                   const int* __restrict__ rowp, const int* __restrict__ ent,
                   short* __restrict__ dxn)
{
    const int n = blockIdx.x;
    const int c = threadIdx.x;
    const int b = rowp[n], e2 = rowp[n + 1];
    float ave = 0.f, dv = 0.f;
    for (int k = b; k < e2; ++k) {
        int v = ent[k];
        int e = v & 0x7fffffff;
        float x = b2f(xe[(size_t)e * 128 + c]);
        ave += x;
        dv  += (v < 0) ? -x : x;
    }
    size_t base = (size_t)n * 384;
    dxn[base + c]       = f2b(0.5f * ave);
    dxn[base + 128 + c] = f2b(dv);
    dxn[base + 256 + c] = xn[(size_t)n * 128 + c];
}

// online max+sum pass, then subtract pass; float4 loads; alpha fused in block 0
__global__ __launch_bounds__(256)
void log_softmax_k(float* __restrict__ y, const float* __restrict__ alpha,
                   float* __restrict__ alpha_out)
{
    const int row = blockIdx.x;
    float* p = y + (size_t)row * NNODES;
    __shared__ float redm[256], reds[256];
    const int t = threadIdx.x;

    if (row == 0 && t == 0) alpha_out[0] = 1.f / (1.f + expf(-alpha[0]));

    float m = -INFINITY, s = 0.f;
    for (int i = t; i < NNODES / 4; i += 256) {
        f32x4 v = ((const f32x4*)p)[i];
        #pragma unroll
        for (int j = 0; j < 4; ++j) {
            float x = v[j];
            if (x > m) { s = s * __expf(m - x) + 1.f; m = x; }
            else       { s += __expf(x - m); }
        }
    }
    redm[t] = m; reds[t] = s; __syncthreads();
    for (int st = 128; st > 0; st >>= 1) {
        if (t < st) {
            float m2 = redm[t + st], s2 = reds[t + st];
            float mm = fmaxf(redm[t], m2);
            reds[t] = reds[t] * __expf(redm[t] - mm) + s2 * __expf(m2 - mm);
            redm[t] = mm;
        }
        __syncthreads();
    }
    const float lse = redm[0] + logf(reds[0]);

    for (int i = t; i < NNODES / 4; i += 256) {
        f32x4 v = ((const f32x4*)p)[i];
        #pragma unroll
        for (int j = 0; j < 4; ++j) v[j] -= lse;
        ((f32x4*)p)[i] = v;
    }
}

extern "C" void kernel_launch(void* const* d_in, const int* in_sizes, int n_in,
                              void* d_out, int out_size, void* d_ws, size_t ws_size,
                              hipStream_t stream)
{
    const float* xn_in = (const float*)d_in[0];
    const float* xe_in = (const float*)d_in[1];
    const float* K1N   = (const float*)d_in[2];
    const float* K2N   = (const float*)d_in[3];
    const float* K1E   = (const float*)d_in[4];
    const float* K2E   = (const float*)d_in[5];
    const float* KNc   = (const float*)d_in[6];
    const float* KE1   = (const float*)d_in[7];
    const float* KE2   = (const float*)d_in[8];
    const float* KN1   = (const float*)d_in[9];
    const float* KN2   = (const float*)d_in[10];
    const float* l1w   = (const float*)d_in[11];
    const float* l1b   = (const float*)d_in[12];
    const float* l2w   = (const float*)d_in[13];
    const float* l2b   = (const float*)d_in[14];
    const float* alpha = (const float*)d_in[15];
    const int*   I     = (const int*)d_in[16];
    const int*   J     = (const int*)d_in[17];
    float* out = (float*)d_out;

    char* wsp = (char*)d_ws;
    auto alloc = [&](size_t bytes) -> char* {
        char* p = wsp; wsp += (bytes + 255) & ~(size_t)255; return p;
    };
    short* xn_buf = (short*)alloc((size_t)NNODES * 128 * 2);   // 2 MB
    short* xe_buf = (short*)alloc((size_t)NEDGES * 128 * 2);   // 16 MB
    short* t_e    = (short*)alloc((size_t)NEDGES * 256 * 2);   // 32 MB
    short* t_n    = (short*)alloc((size_t)NNODES * 256 * 2);   // 4 MB
    short* dxn_in = (short*)alloc((size_t)NNODES * 384 * 2);   // 6 MB
    short* xnc    = (short*)alloc((size_t)NNODES * 128 * 2);   // 2 MB
    short* x1     = (short*)alloc((size_t)NNODES * 256 * 2);   // 4 MB
    short* K2Nb   = (short*)alloc(128 * 128 * 2);
    short* K2Eb   = (short*)alloc(128 * 128 * 2);
    short* KNcb   = (short*)alloc(128 * 128 * 2);
    short* l1wb   = (short*)alloc(256 * 128 * 2);
    short* l2wb   = (short*)alloc((size_t)8192 * 256 * 2);     // 4.2 MB
    short* KE1b   = (short*)alloc((size_t)8 * 256 * 384 * 2);  // 1.6 MB
    short* KE2b   = (short*)alloc((size_t)8 * 128 * 256 * 2);
    short* KN1b   = (short*)alloc((size_t)8 * 256 * 384 * 2);
    short* KN2b   = (short*)alloc((size_t)8 * 128 * 256 * 2);
    int*   deg    = (int*)alloc((size_t)NNODES * 4);
    int*   rowp   = (int*)alloc((size_t)(NNODES + 8) * 4);
    int*   cur    = (int*)alloc((size_t)NNODES * 4);
    int*   ent    = (int*)alloc((size_t)2 * NEDGES * 4);
    float* sacc   = (float*)alloc(20 * NSLOTS * 2 * 4);        // 20 slot regions

    const dim3 blk(256);
    auto region = [&](int r) { return sacc + (size_t)r * NSLOTS * 2; };

    // ---- one-shot zeroing + weight conversion + CSR build ----
    hipMemsetAsync(sacc, 0, 20 * NSLOTS * 2 * 4, stream);
    hipMemsetAsync(deg, 0, (size_t)NNODES * 4, stream);

    CvtJobs jobs;
    jobs.src[0] = K2N; jobs.dst[0] = K2Nb; jobs.n[0] = 128 * 128;
    jobs.src[1] = K2E; jobs.dst[1] = K2Eb; jobs.n[1] = 128 * 128;
    jobs.src[2] = KNc; jobs.dst[2] = KNcb; jobs.n[2] = 128 * 128;
    jobs.src[3] = l1w; jobs.dst[3] = l1wb; jobs.n[3] = 256 * 128;
    jobs.src[4] = l2w; jobs.dst[4] = l2wb; jobs.n[4] = 8192 * 256;
    jobs.src[5] = KE1; jobs.dst[5] = KE1b; jobs.n[5] = 8 * 256 * 384;
    jobs.src[6] = KE2; jobs.dst[6] = KE2b; jobs.n[6] = 8 * 128 * 256;
    jobs.src[7] = KN1; jobs.dst[7] = KN1b; jobs.n[7] = 8 * 256 * 384;
    jobs.src[8] = KN2; jobs.dst[8] = KN2b; jobs.n[8] = 8 * 128 * 256;
    cvt_all_k<<<dim3(2048), blk, 0, stream>>>(jobs);

    csr_count_k<<<dim3(NEDGES / 256), blk, 0, stream>>>(I, J, deg);
    csr_scan_k<<<dim3(1), dim3(1024), 0, stream>>>(deg, rowp, cur);
    csr_fill_k<<<dim3(NEDGES / 256), blk, 0, stream>>>(I, J, cur, ent);

    const float invN128 = 1.f / (128.f * NNODES);
    const float invE128 = 1.f / (128.f * NEDGES);
    const float invN256 = 1.f / (256.f * NNODES);
    const float invE256 = 1.f / (256.f * NEDGES);

    // ---- opening: node (stats region 0) ----
    open_gemm_k<3, 16><<<dim3(NNODES / 32), blk, 0, stream>>>(K1N, xn_in, xn_buf, NNODES, region(0));
    mfma_gemm_k<1, false, false, 0, false><<<dim3(NNODES / 128, 1), blk, 0, stream>>>(
        K2Nb, xn_buf, xn_buf, 128, 128, nullptr, nullptr, nullptr, nullptr,
        region(0), invN128, nullptr, nullptr, 0.f, nullptr, 0);

    // ---- opening: edge (stats region 1) ----
    open_gemm_k<16, 16><<<dim3(NEDGES / 32), blk, 0, stream>>>(K1E, xe_in, xe_buf, NEDGES, region(1));
    mfma_gemm_k<1, false, false, 0, false><<<dim3(NEDGES / 128, 1), blk, 0, stream>>>(
        K2Eb, xe_buf, xe_buf, 128, 128, nullptr, nullptr, nullptr, nullptr,
        region(1), invE128, nullptr, nullptr, 0.f, nullptr, 0);

    // ---- wave layers (regions 2+2l edge, 3+2l node) ----
    for (int l = 0; l < 8; ++l) {
        const short* ke1 = KE1b + (size_t)l * 256 * 384;
        const short* ke2 = KE2b + (size_t)l * 128 * 256;
        const short* kn1 = KN1b + (size_t)l * 256 * 384;
        const short* kn2 = KN2b + (size_t)l * 128 * 256;
        float* regE = region(2 + 2 * l);
        float* regN = region(3 + 2 * l);

        // edge: GEMM1 (fused concat-gather) -> stats regE
        mfma_gemm_k<2, true, false, 0, false><<<dim3(NEDGES / 128, 2), blk, 0, stream>>>(
            ke1, nullptr, t_e, 384, 256, xn_buf, xe_buf, I, J,
            nullptr, 0.f, regE, nullptr, 0.f, nullptr, 0);
        // edge: GEMM2 (LN from regE, residual into xe_buf)
        mfma_gemm_k<1, false, true, 0, false><<<dim3(NEDGES / 128, 1), blk, 0, stream>>>(
            ke2, t_e, xe_buf, 256, 128, nullptr, nullptr, nullptr, nullptr,
            regE, invE256, nullptr, xe_buf, 0.1f, nullptr, 0);

        // node concat via CSR gather (no atomics)
        gather_node_k<<<dim3(NNODES), dim3(128), 0, stream>>>(xe_buf, xn_buf, rowp, ent, dxn_in);

        // node: GEMM1 -> stats regN
        mfma_gemm_k<0, true, false, 0, false><<<dim3(NNODES / 128, 2), blk, 0, stream>>>(
            kn1, dxn_in, t_n, 384, 256, nullptr, nullptr, nullptr, nullptr,
            nullptr, 0.f, regN, nullptr, 0.f, nullptr, 0);
        // node: GEMM2 (LN from regN, residual into xn_buf)
        mfma_gemm_k<1, false, true, 0, false><<<dim3(NNODES / 128, 1), blk, 0, stream>>>(
            kn2, t_n, xn_buf, 256, 128, nullptr, nullptr, nullptr, nullptr,
            regN, invN256, nullptr, xn_buf, 0.1f, nullptr, 0);
    }

    // ---- close + head ----
    mfma_gemm_k<0, false, false, 0, false><<<dim3(NNODES / 128, 1), blk, 0, stream>>>(
        KNcb, xn_buf, xnc, 128, 128, nullptr, nullptr, nullptr, nullptr,
        nullptr, 0.f, nullptr, nullptr, 0.f, nullptr, 0);
    mfma_gemm_k<0, false, false, 2, false><<<dim3(NNODES / 128, 2), blk, 0, stream>>>(
        l1wb, xnc, x1, 128, 256, nullptr, nullptr, nullptr, nullptr,
        nullptr, 0.f, nullptr, nullptr, 0.f, l1b, 0);
    mfma_gemm_k<0, false, false, 1, true><<<dim3(NNODES / 128, 8192 / 128), blk, 0, stream>>>(
        l2wb, x1, out, 256, 8192, nullptr, nullptr, nullptr, nullptr,
        nullptr, 0.f, nullptr, nullptr, 0.f, l2b, 8192);

    log_softmax_k<<<dim3(NNODES), blk, 0, stream>>>(out, alpha, out + (size_t)NNODES * NNODES);
}